// Round 1
// baseline (1950.481 us; speedup 1.0000x reference)
//
#include <hip/hip_runtime.h>
#include <hip/hip_bf16.h>

typedef unsigned int  u32;
typedef unsigned short u16;

typedef __bf16 bf16x8 __attribute__((ext_vector_type(8)));
typedef float  f32x4  __attribute__((ext_vector_type(4)));

#define D2048 2048
#define SCALE 0.022097086912079612f

__device__ __forceinline__ u32 f2bfbits(float f) {
    u32 u = __float_as_uint(f);
    return (u + 0x7FFFu + ((u >> 16) & 1u)) >> 16;   // RNE
}
__device__ __forceinline__ u32 pack2(float a, float b) {
    return f2bfbits(a) | (f2bfbits(b) << 16);
}
__device__ __forceinline__ float bf2f(u32 h) {
    return __uint_as_float(h << 16);
}
__device__ __forceinline__ void unpack8(uint4 v, float* f) {
    f[0] = bf2f(v.x & 0xFFFFu); f[1] = bf2f(v.x >> 16);
    f[2] = bf2f(v.y & 0xFFFFu); f[3] = bf2f(v.y >> 16);
    f[4] = bf2f(v.z & 0xFFFFu); f[5] = bf2f(v.z >> 16);
    f[6] = bf2f(v.w & 0xFFFFu); f[7] = bf2f(v.w >> 16);
}
__device__ __forceinline__ float sigmf(float x) { return 1.f / (1.f + __expf(-x)); }
__device__ __forceinline__ float tanhf_(float x) {
    x = fminf(15.f, fmaxf(-15.f, x));
    float e = __expf(2.f * x);
    return (e - 1.f) / (e + 1.f);
}

// ---------------------------------------------------------------------------
// fp32 -> bf16 conversion (vectorized by 4)
// ---------------------------------------------------------------------------
__global__ __launch_bounds__(256) void cvt_f32_bf16(const float* __restrict__ in,
                                                    u16* __restrict__ out, int n4) {
    int i = blockIdx.x * 256 + threadIdx.x;
    if (i >= n4) return;
    float4 v = reinterpret_cast<const float4*>(in)[i];
    uint2 p;
    p.x = pack2(v.x, v.y);
    p.y = pack2(v.z, v.w);
    reinterpret_cast<uint2*>(out)[i] = p;
}

// ---------------------------------------------------------------------------
// GEMM: C[M][N] = A[M][K](bf16) * B[N][K](f32, converted inline)^T (+bias)
// 128x128 tile, BK=64, 4 waves, mfma_f32_16x16x32_bf16, fp32 accum.
// LDS rows padded to 72 bf16 (144B) -> conflict-free ds_read_b128.
// ---------------------------------------------------------------------------
template <bool HAS_BIAS, bool OUT_BF16>
__global__ __launch_bounds__(256) void gemm_bt(const u16* __restrict__ A,
                                               const float* __restrict__ B,
                                               const float* __restrict__ bias,
                                               void* __restrict__ Cout,
                                               int M, int N, int K) {
    constexpr int LSTR = 72;  // bf16 elems per LDS row (64 + 8 pad)
    __shared__ u16 Abuf[128 * LSTR];
    __shared__ u16 Bbuf[128 * LSTR];

    const int tid  = threadIdx.x;
    const int lane = tid & 63;
    const int wave = tid >> 6;
    const int wr   = (wave >> 1) * 64;   // wave row offset in tile
    const int wc   = (wave & 1) * 64;    // wave col offset in tile
    const int rowBase = blockIdx.y * 128;
    const int colBase = blockIdx.x * 128;
    const int srow  = tid >> 3;          // 0..31 (staging row, step 32)
    const int sslot = tid & 7;           // 0..7  (8 bf16 per slot)
    const int l15 = lane & 15, l4 = lane >> 4;

    f32x4 acc[4][4];
#pragma unroll
    for (int i = 0; i < 4; i++)
#pragma unroll
        for (int j = 0; j < 4; j++) acc[i][j] = f32x4{0.f, 0.f, 0.f, 0.f};

    for (int k0 = 0; k0 < K; k0 += 64) {
#pragma unroll
        for (int it = 0; it < 4; ++it) {
            int r  = srow + it * 32;
            int ar = rowBase + r;
            ar = (ar < M) ? ar : (M - 1);
            uint4 av = *reinterpret_cast<const uint4*>(A + (size_t)ar * K + k0 + sslot * 8);
            const float* bp = B + (size_t)(colBase + r) * K + k0 + sslot * 8;
            float4 b0 = *reinterpret_cast<const float4*>(bp);
            float4 b1 = *reinterpret_cast<const float4*>(bp + 4);
            uint4 bv;
            bv.x = pack2(b0.x, b0.y);
            bv.y = pack2(b0.z, b0.w);
            bv.z = pack2(b1.x, b1.y);
            bv.w = pack2(b1.z, b1.w);
            *reinterpret_cast<uint4*>(&Abuf[r * LSTR + sslot * 8]) = av;
            *reinterpret_cast<uint4*>(&Bbuf[r * LSTR + sslot * 8]) = bv;
        }
        __syncthreads();
#pragma unroll
        for (int kk = 0; kk < 2; ++kk) {
            bf16x8 af[4], bfr[4];
#pragma unroll
            for (int i = 0; i < 4; i++) {
                af[i]  = *reinterpret_cast<const bf16x8*>(
                    &Abuf[(wr + i * 16 + l15) * LSTR + kk * 32 + l4 * 8]);
                bfr[i] = *reinterpret_cast<const bf16x8*>(
                    &Bbuf[(wc + i * 16 + l15) * LSTR + kk * 32 + l4 * 8]);
            }
#pragma unroll
            for (int i = 0; i < 4; i++)
#pragma unroll
                for (int j = 0; j < 4; j++)
                    acc[i][j] = __builtin_amdgcn_mfma_f32_16x16x32_bf16(af[i], bfr[j],
                                                                        acc[i][j], 0, 0, 0);
        }
        __syncthreads();
    }

    // epilogue: C/D layout col=lane&15, row=(lane>>4)*4+reg
#pragma unroll
    for (int i = 0; i < 4; i++) {
        int row0 = rowBase + wr + i * 16 + l4 * 4;
#pragma unroll
        for (int j = 0; j < 4; j++) {
            int col = colBase + wc + j * 16 + l15;
            float bv = HAS_BIAS ? bias[col] : 0.f;
#pragma unroll
            for (int rr = 0; rr < 4; rr++) {
                int row = row0 + rr;
                if (row < M) {
                    float val = acc[i][j][rr] + bv;
                    if (OUT_BF16)
                        ((u16*)Cout)[(size_t)row * N + col] = (u16)f2bfbits(val);
                    else
                        ((float*)Cout)[(size_t)row * N + col] = val;
                }
            }
        }
    }
}

// ---------------------------------------------------------------------------
// Attention over 5-windows. One block per window n = b*16+t.
// q/k/v rows are gathered from the per-image projections (rows b*20+t+i).
// ---------------------------------------------------------------------------
__global__ __launch_bounds__(256) void attn_win5(const u16* __restrict__ q0,
                                                 const u16* __restrict__ k0,
                                                 const u16* __restrict__ v0,
                                                 u16* __restrict__ att) {
    int n = blockIdx.x;  // 0..1023
    int b = n >> 4, t = n & 15;
    int tid = threadIdx.x, lane = tid & 63, wave = tid >> 6;
    int d0 = tid * 8;
    size_t base = (size_t)(b * 20 + t) * D2048;

    float qv[5][8];
#pragma unroll
    for (int i = 0; i < 5; i++) {
        uint4 v = *reinterpret_cast<const uint4*>(q0 + base + (size_t)i * D2048 + d0);
        unpack8(v, qv[i]);
    }
    float part[25];
#pragma unroll
    for (int p = 0; p < 25; p++) part[p] = 0.f;
#pragma unroll
    for (int m = 0; m < 5; m++) {
        float kv[8];
        uint4 v = *reinterpret_cast<const uint4*>(k0 + base + (size_t)m * D2048 + d0);
        unpack8(v, kv);
#pragma unroll
        for (int l = 0; l < 5; l++)
#pragma unroll
            for (int j = 0; j < 8; j++) part[l * 5 + m] += qv[l][j] * kv[j];
    }
#pragma unroll
    for (int p = 0; p < 25; p++) {
        float s = part[p];
#pragma unroll
        for (int msk = 32; msk; msk >>= 1) s += __shfl_xor(s, msk, 64);
        part[p] = s;
    }
    __shared__ float wred[4][25];
    __shared__ float wmat[25];
    if (lane == 0) {
#pragma unroll
        for (int p = 0; p < 25; p++) wred[wave][p] = part[p];
    }
    __syncthreads();
    if (tid < 5) {
        int l = tid;
        float dv[5], mx = -1e30f;
#pragma unroll
        for (int m = 0; m < 5; m++) {
            dv[m] = (wred[0][l * 5 + m] + wred[1][l * 5 + m] + wred[2][l * 5 + m] +
                     wred[3][l * 5 + m]) * SCALE;
            mx = fmaxf(mx, dv[m]);
        }
        float ssum = 0.f;
#pragma unroll
        for (int m = 0; m < 5; m++) { dv[m] = __expf(dv[m] - mx); ssum += dv[m]; }
        float inv = 1.f / ssum;
#pragma unroll
        for (int m = 0; m < 5; m++) wmat[l * 5 + m] = dv[m] * inv;
    }
    __syncthreads();

    float oacc[5][8];
#pragma unroll
    for (int l = 0; l < 5; l++)
#pragma unroll
        for (int j = 0; j < 8; j++) oacc[l][j] = 0.f;
#pragma unroll
    for (int m = 0; m < 5; m++) {
        float vv[8];
        uint4 v = *reinterpret_cast<const uint4*>(v0 + base + (size_t)m * D2048 + d0);
        unpack8(v, vv);
#pragma unroll
        for (int l = 0; l < 5; l++) {
            float w = wmat[l * 5 + m];
#pragma unroll
            for (int j = 0; j < 8; j++) oacc[l][j] += w * vv[j];
        }
    }
#pragma unroll
    for (int l = 0; l < 5; l++) {
        uint4 p;
        p.x = pack2(oacc[l][0], oacc[l][1]);
        p.y = pack2(oacc[l][2], oacc[l][3]);
        p.z = pack2(oacc[l][4], oacc[l][5]);
        p.w = pack2(oacc[l][6], oacc[l][7]);
        *reinterpret_cast<uint4*>(att + (size_t)(n * 5 + l) * D2048 + d0) = p;
    }
}

// ---------------------------------------------------------------------------
// Attention over seq-16. One block per output row r = b*16 + l.
// ---------------------------------------------------------------------------
__global__ __launch_bounds__(256) void attn_seq16(const u16* __restrict__ q2,
                                                  const u16* __restrict__ k2,
                                                  const u16* __restrict__ v2,
                                                  u16* __restrict__ att2) {
    int r = blockIdx.x;  // 0..1023
    int b = r >> 4;
    int tid = threadIdx.x, lane = tid & 63, wave = tid >> 6;
    int d0 = tid * 8;
    size_t kbase = (size_t)b * 16 * D2048;

    float qv[8];
    {
        uint4 v = *reinterpret_cast<const uint4*>(q2 + (size_t)r * D2048 + d0);
        unpack8(v, qv);
    }
    float part[16];
#pragma unroll
    for (int m = 0; m < 16; m++) part[m] = 0.f;
#pragma unroll
    for (int m = 0; m < 16; m++) {
        float kv[8];
        uint4 v = *reinterpret_cast<const uint4*>(k2 + kbase + (size_t)m * D2048 + d0);
        unpack8(v, kv);
#pragma unroll
        for (int j = 0; j < 8; j++) part[m] += qv[j] * kv[j];
    }
#pragma unroll
    for (int m = 0; m < 16; m++) {
        float s = part[m];
#pragma unroll
        for (int msk = 32; msk; msk >>= 1) s += __shfl_xor(s, msk, 64);
        part[m] = s;
    }
    __shared__ float wred[4][16];
    __shared__ float wmat[16];
    if (lane == 0) {
#pragma unroll
        for (int m = 0; m < 16; m++) wred[wave][m] = part[m];
    }
    __syncthreads();
    if (tid == 0) {
        float dv[16], mx = -1e30f;
#pragma unroll
        for (int m = 0; m < 16; m++) {
            dv[m] = (wred[0][m] + wred[1][m] + wred[2][m] + wred[3][m]) * SCALE;
            mx = fmaxf(mx, dv[m]);
        }
        float ssum = 0.f;
#pragma unroll
        for (int m = 0; m < 16; m++) { dv[m] = __expf(dv[m] - mx); ssum += dv[m]; }
        float inv = 1.f / ssum;
#pragma unroll
        for (int m = 0; m < 16; m++) wmat[m] = dv[m] * inv;
    }
    __syncthreads();

    float oacc[8];
#pragma unroll
    for (int j = 0; j < 8; j++) oacc[j] = 0.f;
#pragma unroll
    for (int m = 0; m < 16; m++) {
        float vv[8];
        uint4 v = *reinterpret_cast<const uint4*>(v2 + kbase + (size_t)m * D2048 + d0);
        unpack8(v, vv);
        float w = wmat[m];
#pragma unroll
        for (int j = 0; j < 8; j++) oacc[j] += w * vv[j];
    }
    uint4 p;
    p.x = pack2(oacc[0], oacc[1]);
    p.y = pack2(oacc[2], oacc[3]);
    p.z = pack2(oacc[4], oacc[5]);
    p.w = pack2(oacc[6], oacc[7]);
    *reinterpret_cast<uint4*>(att2 + (size_t)r * D2048 + d0) = p;
}

// ---------------------------------------------------------------------------
// LSTM gate update. Processes 4 consecutive j per thread.
// gates = xg[n] + hW[n] + bih + bhh ; c' = sig(f)c + sig(i)tanh(g); h = sig(o)tanh(c')
// ---------------------------------------------------------------------------
template <bool FIRST>
__global__ __launch_bounds__(256) void lstm_gate(const float* __restrict__ xg,
                                                 int xg_stride,
                                                 const float* __restrict__ hW,
                                                 const float* __restrict__ bih,
                                                 const float* __restrict__ bhh,
                                                 float* __restrict__ c,
                                                 float* __restrict__ h,
                                                 u16* __restrict__ hbf,
                                                 float* __restrict__ hout,
                                                 int rows) {
    int idx = blockIdx.x * 256 + threadIdx.x;
    int total = rows * 512;
    if (idx >= total) return;
    int n  = idx >> 9;
    int j4 = (idx & 511) * 4;

    const float* xr = xg + (size_t)n * xg_stride;
    float4 gi = *reinterpret_cast<const float4*>(xr + j4);
    float4 gf = *reinterpret_cast<const float4*>(xr + 2048 + j4);
    float4 gg = *reinterpret_cast<const float4*>(xr + 4096 + j4);
    float4 go = *reinterpret_cast<const float4*>(xr + 6144 + j4);

    float4 bi1 = *reinterpret_cast<const float4*>(bih + j4);
    float4 bf1 = *reinterpret_cast<const float4*>(bih + 2048 + j4);
    float4 bg1 = *reinterpret_cast<const float4*>(bih + 4096 + j4);
    float4 bo1 = *reinterpret_cast<const float4*>(bih + 6144 + j4);
    float4 bi2 = *reinterpret_cast<const float4*>(bhh + j4);
    float4 bf2 = *reinterpret_cast<const float4*>(bhh + 2048 + j4);
    float4 bg2 = *reinterpret_cast<const float4*>(bhh + 4096 + j4);
    float4 bo2 = *reinterpret_cast<const float4*>(bhh + 6144 + j4);

    gi.x += bi1.x + bi2.x; gi.y += bi1.y + bi2.y; gi.z += bi1.z + bi2.z; gi.w += bi1.w + bi2.w;
    gf.x += bf1.x + bf2.x; gf.y += bf1.y + bf2.y; gf.z += bf1.z + bf2.z; gf.w += bf1.w + bf2.w;
    gg.x += bg1.x + bg2.x; gg.y += bg1.y + bg2.y; gg.z += bg1.z + bg2.z; gg.w += bg1.w + bg2.w;
    go.x += bo1.x + bo2.x; go.y += bo1.y + bo2.y; go.z += bo1.z + bo2.z; go.w += bo1.w + bo2.w;

    if (!FIRST) {
        const float* hr = hW + (size_t)n * 8192;
        float4 hi = *reinterpret_cast<const float4*>(hr + j4);
        float4 hf = *reinterpret_cast<const float4*>(hr + 2048 + j4);
        float4 hg = *reinterpret_cast<const float4*>(hr + 4096 + j4);
        float4 ho = *reinterpret_cast<const float4*>(hr + 6144 + j4);
        gi.x += hi.x; gi.y += hi.y; gi.z += hi.z; gi.w += hi.w;
        gf.x += hf.x; gf.y += hf.y; gf.z += hf.z; gf.w += hf.w;
        gg.x += hg.x; gg.y += hg.y; gg.z += hg.z; gg.w += hg.w;
        go.x += ho.x; go.y += ho.y; go.z += ho.z; go.w += ho.w;
    }
    float4 cc;
    if (FIRST) { cc.x = cc.y = cc.z = cc.w = 0.f; }
    else        cc = *reinterpret_cast<const float4*>(c + (size_t)n * 2048 + j4);

    float cx = sigmf(gf.x) * cc.x + sigmf(gi.x) * tanhf_(gg.x);
    float cy = sigmf(gf.y) * cc.y + sigmf(gi.y) * tanhf_(gg.y);
    float cz = sigmf(gf.z) * cc.z + sigmf(gi.z) * tanhf_(gg.z);
    float cw = sigmf(gf.w) * cc.w + sigmf(gi.w) * tanhf_(gg.w);
    float hx = sigmf(go.x) * tanhf_(cx);
    float hy = sigmf(go.y) * tanhf_(cy);
    float hz = sigmf(go.z) * tanhf_(cz);
    float hw_ = sigmf(go.w) * tanhf_(cw);

    float4 co = {cx, cy, cz, cw};
    float4 ho_ = {hx, hy, hz, hw_};
    *reinterpret_cast<float4*>(c + (size_t)n * 2048 + j4) = co;
    *reinterpret_cast<float4*>(h + (size_t)n * 2048 + j4) = ho_;
    uint2 hp;
    hp.x = pack2(hx, hy);
    hp.y = pack2(hz, hw_);
    *reinterpret_cast<uint2*>(hbf + (size_t)n * 2048 + j4) = hp;
    if (hout) *reinterpret_cast<float4*>(hout + (size_t)n * 2048 + j4) = ho_;
}

// ---------------------------------------------------------------------------
// LayerNorm over last dim (2048). One block per row. Writes fp32 + bf16 copy.
// ---------------------------------------------------------------------------
__global__ __launch_bounds__(256) void layernorm_k(const float* __restrict__ x,
                                                   const float* __restrict__ g,
                                                   const float* __restrict__ b,
                                                   float* __restrict__ y,
                                                   u16* __restrict__ ybf) {
    int row = blockIdx.x;
    int tid = threadIdx.x, lane = tid & 63, wave = tid >> 6;
    const float* xr = x + (size_t)row * D2048;
    int j = tid * 8;
    float4 v1 = *reinterpret_cast<const float4*>(xr + j);
    float4 v2 = *reinterpret_cast<const float4*>(xr + j + 4);
    float s  = v1.x + v1.y + v1.z + v1.w + v2.x + v2.y + v2.z + v2.w;
    float s2 = v1.x * v1.x + v1.y * v1.y + v1.z * v1.z + v1.w * v1.w +
               v2.x * v2.x + v2.y * v2.y + v2.z * v2.z + v2.w * v2.w;
#pragma unroll
    for (int msk = 32; msk; msk >>= 1) {
        s  += __shfl_xor(s, msk, 64);
        s2 += __shfl_xor(s2, msk, 64);
    }
    __shared__ float red[4][2];
    if (lane == 0) { red[wave][0] = s; red[wave][1] = s2; }
    __syncthreads();
    s  = red[0][0] + red[1][0] + red[2][0] + red[3][0];
    s2 = red[0][1] + red[1][1] + red[2][1] + red[3][1];
    float mu  = s * (1.f / 2048.f);
    float var = s2 * (1.f / 2048.f) - mu * mu;
    float rs  = __frsqrt_rn(var + 1e-5f);

    float4 g1 = *reinterpret_cast<const float4*>(g + j);
    float4 g2 = *reinterpret_cast<const float4*>(g + j + 4);
    float4 b1 = *reinterpret_cast<const float4*>(b + j);
    float4 b2 = *reinterpret_cast<const float4*>(b + j + 4);
    float o[8];
    o[0] = (v1.x - mu) * rs * g1.x + b1.x;
    o[1] = (v1.y - mu) * rs * g1.y + b1.y;
    o[2] = (v1.z - mu) * rs * g1.z + b1.z;
    o[3] = (v1.w - mu) * rs * g1.w + b1.w;
    o[4] = (v2.x - mu) * rs * g2.x + b2.x;
    o[5] = (v2.y - mu) * rs * g2.y + b2.y;
    o[6] = (v2.z - mu) * rs * g2.z + b2.z;
    o[7] = (v2.w - mu) * rs * g2.w + b2.w;
    float4 o1 = {o[0], o[1], o[2], o[3]};
    float4 o2 = {o[4], o[5], o[6], o[7]};
    float* yr = y + (size_t)row * D2048;
    *reinterpret_cast<float4*>(yr + j)     = o1;
    *reinterpret_cast<float4*>(yr + j + 4) = o2;
    uint4 p;
    p.x = pack2(o[0], o[1]);
    p.y = pack2(o[2], o[3]);
    p.z = pack2(o[4], o[5]);
    p.w = pack2(o[6], o[7]);
    *reinterpret_cast<uint4*>(ybf + (size_t)row * D2048 + j) = p;
}

// ---------------------------------------------------------------------------
static inline void launch_gemm(hipStream_t s, const u16* A, const float* B,
                               const float* bias, void* C, int M, int N, int K,
                               bool outbf) {
    dim3 grid(N / 128, (M + 127) / 128);
    if (outbf)
        gemm_bt<true, true><<<grid, 256, 0, s>>>(A, B, bias, C, M, N, K);
    else
        gemm_bt<false, false><<<grid, 256, 0, s>>>(A, B, nullptr, C, M, N, K);
}

extern "C" void kernel_launch(void* const* d_in, const int* in_sizes, int n_in,
                              void* d_out, int out_size, void* d_ws, size_t ws_size,
                              hipStream_t stream) {
    const float* fc      = (const float*)d_in[0];
    const float* nsa_Wq  = (const float*)d_in[1];
    const float* nsa_Wk  = (const float*)d_in[2];
    const float* nsa_Wv  = (const float*)d_in[3];
    const float* nsa_bq  = (const float*)d_in[4];
    const float* nsa_bk  = (const float*)d_in[5];
    const float* nsa_bv  = (const float*)d_in[6];
    const float* nsa_Wih = (const float*)d_in[7];
    const float* nsa_Whh = (const float*)d_in[8];
    const float* nsa_bih = (const float*)d_in[9];
    const float* nsa_bhh = (const float*)d_in[10];
    const float* sa_Wq   = (const float*)d_in[11];
    const float* sa_Wk   = (const float*)d_in[12];
    const float* sa_Wv   = (const float*)d_in[13];
    const float* sa_bq   = (const float*)d_in[14];
    const float* sa_bk   = (const float*)d_in[15];
    const float* sa_bv   = (const float*)d_in[16];
    const float* sa_Wih  = (const float*)d_in[17];
    const float* sa_Whh  = (const float*)d_in[18];
    const float* sa_bih  = (const float*)d_in[19];
    const float* sa_bhh  = (const float*)d_in[20];
    const float* ln_g    = (const float*)d_in[21];
    const float* ln_b    = (const float*)d_in[22];

    float* outF   = (float*)d_out;
    float* out_sa = outF;            // (64,2048)
    float* out_ln = outF + 131072;   // (64,16,2048)

    char* W = (char*)d_ws;
    u16*   Xbf  = (u16*)(W);                     // 1280x2048 bf16
    u16*   q0   = (u16*)(W + 5242880);
    u16*   k0   = (u16*)(W + 10485760);
    u16*   v0   = (u16*)(W + 15728640);
    u16*   att1 = (u16*)(W + 20971520);          // 5120x2048 bf16
    float* xg1  = (float*)(W + 41943040);        // 5120x8192 f32
    float* hW1  = (float*)(W + 209715200);       // 1024x8192 f32
    float* h1   = (float*)(W + 243269632);       // 1024x2048 f32
    float* c1   = (float*)(W + 251658240);       // 1024x2048 f32
    u16*   h1bf = (u16*)(W + 260046848);         // 1024x2048 bf16
    // stage-2 aliases (regions dead by the time these are written)
    u16*   lnbf = Xbf;
    u16*   q2 = q0, *k2 = k0, *v2 = v0;
    u16*   att2 = att1;
    float* xg2 = xg1;                            // 1024x8192 f32
    float* hW2 = hW1;                            // 64x8192 f32
    float* h2 = h1, *c2 = c1;
    u16*   h2bf = h1bf;

    // 0) fc_feats -> bf16
    cvt_f32_bf16<<<2560, 256, 0, stream>>>(fc, Xbf, 655360);

    // 1) nsa QKV on the 1280 unique rows
    launch_gemm(stream, Xbf, nsa_Wq, nsa_bq, q0, 1280, 2048, 2048, true);
    launch_gemm(stream, Xbf, nsa_Wk, nsa_bk, k0, 1280, 2048, 2048, true);
    launch_gemm(stream, Xbf, nsa_Wv, nsa_bv, v0, 1280, 2048, 2048, true);

    // 2) windowed attention
    attn_win5<<<1024, 256, 0, stream>>>(q0, k0, v0, att1);

    // 3) xg1 = att1 @ Wih^T  (bias added in gate kernel)
    launch_gemm(stream, att1, nsa_Wih, nullptr, xg1, 5120, 8192, 2048, false);

    // 4) nsa LSTM over 5 steps (rows = 1024 windows)
    lstm_gate<true><<<2048, 256, 0, stream>>>(xg1, 40960, nullptr, nsa_bih, nsa_bhh,
                                              c1, h1, h1bf, nullptr, 1024);
    for (int t = 1; t < 5; ++t) {
        launch_gemm(stream, h1bf, nsa_Whh, nullptr, hW1, 1024, 8192, 2048, false);
        lstm_gate<false><<<2048, 256, 0, stream>>>(xg1 + (size_t)t * 8192, 40960, hW1,
                                                   nsa_bih, nsa_bhh, c1, h1, h1bf,
                                                   nullptr, 1024);
    }

    // 5) LayerNorm -> output 1 (fp32) + bf16 copy for stage 2
    layernorm_k<<<1024, 256, 0, stream>>>(h1, ln_g, ln_b, out_ln, lnbf);

    // 6) sa QKV
    launch_gemm(stream, lnbf, sa_Wq, sa_bq, q2, 1024, 2048, 2048, true);
    launch_gemm(stream, lnbf, sa_Wk, sa_bk, k2, 1024, 2048, 2048, true);
    launch_gemm(stream, lnbf, sa_Wv, sa_bv, v2, 1024, 2048, 2048, true);

    // 7) seq-16 attention
    attn_seq16<<<1024, 256, 0, stream>>>(q2, k2, v2, att2);

    // 8) xg2 = att2 @ saWih^T
    launch_gemm(stream, att2, sa_Wih, nullptr, xg2, 1024, 8192, 2048, false);

    // 9) sa LSTM over 16 steps (rows = 64)
    lstm_gate<true><<<128, 256, 0, stream>>>(xg2, 131072, nullptr, sa_bih, sa_bhh,
                                             c2, h2, h2bf, nullptr, 64);
    for (int t = 1; t < 16; ++t) {
        launch_gemm(stream, h2bf, sa_Whh, nullptr, hW2, 64, 8192, 2048, false);
        lstm_gate<false><<<128, 256, 0, stream>>>(xg2 + (size_t)t * 8192, 131072, hW2,
                                                  sa_bih, sa_bhh, c2, h2, h2bf,
                                                  (t == 15) ? out_sa : nullptr, 64);
    }
}

// Round 2
// 1311.779 us; speedup vs baseline: 1.4869x; 1.4869x over previous
//
#include <hip/hip_runtime.h>
#include <hip/hip_bf16.h>

typedef unsigned int  u32;
typedef unsigned short u16;

typedef __bf16 bf16x8 __attribute__((ext_vector_type(8)));
typedef float  f32x4  __attribute__((ext_vector_type(4)));

#define D2048 2048
#define SCALE 0.022097086912079612f

__device__ __forceinline__ u32 f2bfbits(float f) {
    u32 u = __float_as_uint(f);
    return (u + 0x7FFFu + ((u >> 16) & 1u)) >> 16;   // RNE
}
__device__ __forceinline__ u32 pack2(float a, float b) {
    return f2bfbits(a) | (f2bfbits(b) << 16);
}
__device__ __forceinline__ float bf2f(u32 h) {
    return __uint_as_float(h << 16);
}
__device__ __forceinline__ void unpack8(uint4 v, float* f) {
    f[0] = bf2f(v.x & 0xFFFFu); f[1] = bf2f(v.x >> 16);
    f[2] = bf2f(v.y & 0xFFFFu); f[3] = bf2f(v.y >> 16);
    f[4] = bf2f(v.z & 0xFFFFu); f[5] = bf2f(v.z >> 16);
    f[6] = bf2f(v.w & 0xFFFFu); f[7] = bf2f(v.w >> 16);
}
__device__ __forceinline__ float sigmf(float x) { return 1.f / (1.f + __expf(-x)); }
__device__ __forceinline__ float tanhf_(float x) {
    x = fminf(15.f, fmaxf(-15.f, x));
    float e = __expf(2.f * x);
    return (e - 1.f) / (e + 1.f);
}

// async global->LDS, 16B per lane. LDS dest is wave-uniform base + lane*16.
__device__ __forceinline__ void gload_lds16(const u16* g, u16* l) {
    __builtin_amdgcn_global_load_lds(
        (const __attribute__((address_space(1))) unsigned int*)g,
        (__attribute__((address_space(3))) unsigned int*)l,
        16, 0, 0);
}

// ---------------------------------------------------------------------------
// fp32 -> bf16 conversion (vectorized by 4)
// ---------------------------------------------------------------------------
__global__ __launch_bounds__(256) void cvt_f32_bf16(const float* __restrict__ in,
                                                    u16* __restrict__ out, int n4) {
    int i = blockIdx.x * 256 + threadIdx.x;
    if (i >= n4) return;
    float4 v = reinterpret_cast<const float4*>(in)[i];
    uint2 p;
    p.x = pack2(v.x, v.y);
    p.y = pack2(v.z, v.w);
    reinterpret_cast<uint2*>(out)[i] = p;
}

// ---------------------------------------------------------------------------
// GEMM: C[M][N] = A[M][K](bf16, row stride lda) * B[N][K](bf16)^T (+bias)
// m97 structure: 128x128 tile, BK=64, 4 waves, global_load_lds width-16,
// linear LDS [128][64], single-buffered 2-barrier loop, fp32 accum.
// Requires M%128==0, N%128==0, K%64==0.
// ---------------------------------------------------------------------------
template <bool HAS_BIAS, bool OUT_BF16>
__global__ __launch_bounds__(256) void gemm_bt(const u16* __restrict__ A, int lda,
                                               const u16* __restrict__ B,
                                               const float* __restrict__ bias,
                                               void* __restrict__ Cout,
                                               int M, int N, int K) {
    __shared__ u16 Abuf[128 * 64];
    __shared__ u16 Bbuf[128 * 64];

    const int tid  = threadIdx.x;
    const int lane = tid & 63;
    const int wave = tid >> 6;
    const int wr   = (wave >> 1) * 64;
    const int wc   = (wave & 1) * 64;
    const int rowBase = blockIdx.y * 128;
    const int colBase = blockIdx.x * 128;
    const int l15 = lane & 15, l4 = lane >> 4;
    const int srow = lane >> 3;        // 0..7
    const int scol = (lane & 7) * 8;   // bf16 col within BK

    const u16* ga = A + (size_t)(rowBase + wave * 32 + srow) * lda + scol;
    const u16* gb = B + (size_t)(colBase + wave * 32 + srow) * K + scol;
    u16* la = &Abuf[(wave * 32) * 64];
    u16* lb = &Bbuf[(wave * 32) * 64];

    f32x4 acc[4][4];
#pragma unroll
    for (int i = 0; i < 4; i++)
#pragma unroll
        for (int j = 0; j < 4; j++) acc[i][j] = f32x4{0.f, 0.f, 0.f, 0.f};

    for (int k0 = 0; k0 < K; k0 += 64) {
#pragma unroll
        for (int i = 0; i < 4; ++i) {
            gload_lds16(ga + (size_t)(i * 8) * lda + k0, la + i * 8 * 64);
            gload_lds16(gb + (size_t)(i * 8) * K   + k0, lb + i * 8 * 64);
        }
        __syncthreads();
#pragma unroll
        for (int kk = 0; kk < 2; ++kk) {
            bf16x8 af[4], bfr[4];
#pragma unroll
            for (int i = 0; i < 4; i++) {
                af[i]  = *reinterpret_cast<const bf16x8*>(
                    &Abuf[(wr + i * 16 + l15) * 64 + kk * 32 + l4 * 8]);
                bfr[i] = *reinterpret_cast<const bf16x8*>(
                    &Bbuf[(wc + i * 16 + l15) * 64 + kk * 32 + l4 * 8]);
            }
#pragma unroll
            for (int i = 0; i < 4; i++)
#pragma unroll
                for (int j = 0; j < 4; j++)
                    acc[i][j] = __builtin_amdgcn_mfma_f32_16x16x32_bf16(af[i], bfr[j],
                                                                        acc[i][j], 0, 0, 0);
        }
        __syncthreads();
    }

    // C/D layout: col=lane&15, row=(lane>>4)*4+reg
#pragma unroll
    for (int i = 0; i < 4; i++) {
        int row0 = rowBase + wr + i * 16 + l4 * 4;
#pragma unroll
        for (int j = 0; j < 4; j++) {
            int col = colBase + wc + j * 16 + l15;
            float bv = HAS_BIAS ? bias[col] : 0.f;
#pragma unroll
            for (int rr = 0; rr < 4; rr++) {
                float val = acc[i][j][rr] + bv;
                if (OUT_BF16)
                    ((u16*)Cout)[(size_t)(row0 + rr) * N + col] = (u16)f2bfbits(val);
                else
                    ((float*)Cout)[(size_t)(row0 + rr) * N + col] = val;
            }
        }
    }
}

// ---------------------------------------------------------------------------
// Skinny GEMM for the sa recurrence: C_part[kp] = A[64][Kseg] * B[N][Kseg]^T
// Tile 64x128, 4 waves (each 64x32), split-K=4 over gridDim.y.
// Writes 4 fp32 partial buffers of [64][N]; gate kernel sums them.
// ---------------------------------------------------------------------------
__global__ __launch_bounds__(256) void gemm_skinny64(const u16* __restrict__ A,
                                                     const u16* __restrict__ B,
                                                     float* __restrict__ part,
                                                     int N, int K) {
    __shared__ u16 Abuf[64 * 64];
    __shared__ u16 Bbuf[128 * 64];
    const int tid = threadIdx.x, lane = tid & 63, wave = tid >> 6;
    const int colBase = blockIdx.x * 128;
    const int kp = blockIdx.y;
    const int kseg = K >> 2;
    const int kBeg = kp * kseg, kEnd = kBeg + kseg;
    const int l15 = lane & 15, l4 = lane >> 4;
    const int srow = lane >> 3, scol = (lane & 7) * 8;

    const u16* ga = A + (size_t)(wave * 16 + srow) * K + scol;          // rows w*16..+15
    const u16* gb = B + (size_t)(colBase + wave * 32 + srow) * K + scol; // rows w*32..+31
    u16* la = &Abuf[(wave * 16) * 64];
    u16* lb = &Bbuf[(wave * 32) * 64];

    f32x4 acc[4][2];
#pragma unroll
    for (int i = 0; i < 4; i++)
#pragma unroll
        for (int j = 0; j < 2; j++) acc[i][j] = f32x4{0.f, 0.f, 0.f, 0.f};

    for (int k0 = kBeg; k0 < kEnd; k0 += 64) {
#pragma unroll
        for (int i = 0; i < 2; ++i)
            gload_lds16(ga + (size_t)(i * 8) * K + k0, la + i * 8 * 64);
#pragma unroll
        for (int i = 0; i < 4; ++i)
            gload_lds16(gb + (size_t)(i * 8) * K + k0, lb + i * 8 * 64);
        __syncthreads();
#pragma unroll
        for (int kk = 0; kk < 2; ++kk) {
            bf16x8 af[4], bfr[2];
#pragma unroll
            for (int i = 0; i < 4; i++)
                af[i] = *reinterpret_cast<const bf16x8*>(
                    &Abuf[(i * 16 + l15) * 64 + kk * 32 + l4 * 8]);
#pragma unroll
            for (int j = 0; j < 2; j++)
                bfr[j] = *reinterpret_cast<const bf16x8*>(
                    &Bbuf[(wave * 32 + j * 16 + l15) * 64 + kk * 32 + l4 * 8]);
#pragma unroll
            for (int i = 0; i < 4; i++)
#pragma unroll
                for (int j = 0; j < 2; j++)
                    acc[i][j] = __builtin_amdgcn_mfma_f32_16x16x32_bf16(af[i], bfr[j],
                                                                        acc[i][j], 0, 0, 0);
        }
        __syncthreads();
    }

    float* cp = part + (size_t)kp * 64 * N;
#pragma unroll
    for (int i = 0; i < 4; i++) {
        int row0 = i * 16 + l4 * 4;
#pragma unroll
        for (int j = 0; j < 2; j++) {
            int col = colBase + wave * 32 + j * 16 + l15;
#pragma unroll
            for (int rr = 0; rr < 4; rr++)
                cp[(size_t)(row0 + rr) * N + col] = acc[i][j][rr];
        }
    }
}

// ---------------------------------------------------------------------------
// Attention over 5-windows. One block per window n = b*16+t.
// ---------------------------------------------------------------------------
__global__ __launch_bounds__(256) void attn_win5(const u16* __restrict__ q0,
                                                 const u16* __restrict__ k0,
                                                 const u16* __restrict__ v0,
                                                 u16* __restrict__ att) {
    int n = blockIdx.x;  // 0..1023
    int b = n >> 4, t = n & 15;
    int tid = threadIdx.x, lane = tid & 63, wave = tid >> 6;
    int d0 = tid * 8;
    size_t base = (size_t)(b * 20 + t) * D2048;

    float qv[5][8];
#pragma unroll
    for (int i = 0; i < 5; i++) {
        uint4 v = *reinterpret_cast<const uint4*>(q0 + base + (size_t)i * D2048 + d0);
        unpack8(v, qv[i]);
    }
    float part[25];
#pragma unroll
    for (int p = 0; p < 25; p++) part[p] = 0.f;
#pragma unroll
    for (int m = 0; m < 5; m++) {
        float kv[8];
        uint4 v = *reinterpret_cast<const uint4*>(k0 + base + (size_t)m * D2048 + d0);
        unpack8(v, kv);
#pragma unroll
        for (int l = 0; l < 5; l++)
#pragma unroll
            for (int j = 0; j < 8; j++) part[l * 5 + m] += qv[l][j] * kv[j];
    }
#pragma unroll
    for (int p = 0; p < 25; p++) {
        float s = part[p];
#pragma unroll
        for (int msk = 32; msk; msk >>= 1) s += __shfl_xor(s, msk, 64);
        part[p] = s;
    }
    __shared__ float wred[4][25];
    __shared__ float wmat[25];
    if (lane == 0) {
#pragma unroll
        for (int p = 0; p < 25; p++) wred[wave][p] = part[p];
    }
    __syncthreads();
    if (tid < 5) {
        int l = tid;
        float dv[5], mx = -1e30f;
#pragma unroll
        for (int m = 0; m < 5; m++) {
            dv[m] = (wred[0][l * 5 + m] + wred[1][l * 5 + m] + wred[2][l * 5 + m] +
                     wred[3][l * 5 + m]) * SCALE;
            mx = fmaxf(mx, dv[m]);
        }
        float ssum = 0.f;
#pragma unroll
        for (int m = 0; m < 5; m++) { dv[m] = __expf(dv[m] - mx); ssum += dv[m]; }
        float inv = 1.f / ssum;
#pragma unroll
        for (int m = 0; m < 5; m++) wmat[l * 5 + m] = dv[m] * inv;
    }
    __syncthreads();

    float oacc[5][8];
#pragma unroll
    for (int l = 0; l < 5; l++)
#pragma unroll
        for (int j = 0; j < 8; j++) oacc[l][j] = 0.f;
#pragma unroll
    for (int m = 0; m < 5; m++) {
        float vv[8];
        uint4 v = *reinterpret_cast<const uint4*>(v0 + base + (size_t)m * D2048 + d0);
        unpack8(v, vv);
#pragma unroll
        for (int l = 0; l < 5; l++) {
            float w = wmat[l * 5 + m];
#pragma unroll
            for (int j = 0; j < 8; j++) oacc[l][j] += w * vv[j];
        }
    }
#pragma unroll
    for (int l = 0; l < 5; l++) {
        uint4 p;
        p.x = pack2(oacc[l][0], oacc[l][1]);
        p.y = pack2(oacc[l][2], oacc[l][3]);
        p.z = pack2(oacc[l][4], oacc[l][5]);
        p.w = pack2(oacc[l][6], oacc[l][7]);
        *reinterpret_cast<uint4*>(att + (size_t)(n * 5 + l) * D2048 + d0) = p;
    }
}

// ---------------------------------------------------------------------------
// Attention over seq-16. One block per output row r = b*16 + l.
// ---------------------------------------------------------------------------
__global__ __launch_bounds__(256) void attn_seq16(const u16* __restrict__ q2,
                                                  const u16* __restrict__ k2,
                                                  const u16* __restrict__ v2,
                                                  u16* __restrict__ att2) {
    int r = blockIdx.x;  // 0..1023
    int b = r >> 4;
    int tid = threadIdx.x, lane = tid & 63, wave = tid >> 6;
    int d0 = tid * 8;
    size_t kbase = (size_t)b * 16 * D2048;

    float qv[8];
    {
        uint4 v = *reinterpret_cast<const uint4*>(q2 + (size_t)r * D2048 + d0);
        unpack8(v, qv);
    }
    float part[16];
#pragma unroll
    for (int m = 0; m < 16; m++) part[m] = 0.f;
#pragma unroll
    for (int m = 0; m < 16; m++) {
        float kv[8];
        uint4 v = *reinterpret_cast<const uint4*>(k2 + kbase + (size_t)m * D2048 + d0);
        unpack8(v, kv);
#pragma unroll
        for (int j = 0; j < 8; j++) part[m] += qv[j] * kv[j];
    }
#pragma unroll
    for (int m = 0; m < 16; m++) {
        float s = part[m];
#pragma unroll
        for (int msk = 32; msk; msk >>= 1) s += __shfl_xor(s, msk, 64);
        part[m] = s;
    }
    __shared__ float wred[4][16];
    __shared__ float wmat[16];
    if (lane == 0) {
#pragma unroll
        for (int m = 0; m < 16; m++) wred[wave][m] = part[m];
    }
    __syncthreads();
    if (tid == 0) {
        float dv[16], mx = -1e30f;
#pragma unroll
        for (int m = 0; m < 16; m++) {
            dv[m] = (wred[0][m] + wred[1][m] + wred[2][m] + wred[3][m]) * SCALE;
            mx = fmaxf(mx, dv[m]);
        }
        float ssum = 0.f;
#pragma unroll
        for (int m = 0; m < 16; m++) { dv[m] = __expf(dv[m] - mx); ssum += dv[m]; }
        float inv = 1.f / ssum;
#pragma unroll
        for (int m = 0; m < 16; m++) wmat[m] = dv[m] * inv;
    }
    __syncthreads();

    float oacc[8];
#pragma unroll
    for (int j = 0; j < 8; j++) oacc[j] = 0.f;
#pragma unroll
    for (int m = 0; m < 16; m++) {
        float vv[8];
        uint4 v = *reinterpret_cast<const uint4*>(v2 + kbase + (size_t)m * D2048 + d0);
        unpack8(v, vv);
        float w = wmat[m];
#pragma unroll
        for (int j = 0; j < 8; j++) oacc[j] += w * vv[j];
    }
    uint4 p;
    p.x = pack2(oacc[0], oacc[1]);
    p.y = pack2(oacc[2], oacc[3]);
    p.z = pack2(oacc[4], oacc[5]);
    p.w = pack2(oacc[6], oacc[7]);
    *reinterpret_cast<uint4*>(att2 + (size_t)r * D2048 + d0) = p;
}

// ---------------------------------------------------------------------------
// LSTM gate update. NPARTS==0: first step (c=0, no hW). NPARTS>=1: sum NPARTS
// partial hW buffers (stride 64*8192 between partials; row stride 8192).
// ---------------------------------------------------------------------------
template <int NPARTS>
__global__ __launch_bounds__(256) void lstm_gate(const float* __restrict__ xg,
                                                 int xg_stride,
                                                 const float* __restrict__ hW,
                                                 const float* __restrict__ bih,
                                                 const float* __restrict__ bhh,
                                                 float* __restrict__ c,
                                                 float* __restrict__ h,
                                                 u16* __restrict__ hbf,
                                                 float* __restrict__ hout,
                                                 int rows) {
    int idx = blockIdx.x * 256 + threadIdx.x;
    int total = rows * 512;
    if (idx >= total) return;
    int n  = idx >> 9;
    int j4 = (idx & 511) * 4;

    const float* xr = xg + (size_t)n * xg_stride;
    float4 gi = *reinterpret_cast<const float4*>(xr + j4);
    float4 gf = *reinterpret_cast<const float4*>(xr + 2048 + j4);
    float4 gg = *reinterpret_cast<const float4*>(xr + 4096 + j4);
    float4 go = *reinterpret_cast<const float4*>(xr + 6144 + j4);

    float4 bi1 = *reinterpret_cast<const float4*>(bih + j4);
    float4 bf1 = *reinterpret_cast<const float4*>(bih + 2048 + j4);
    float4 bg1 = *reinterpret_cast<const float4*>(bih + 4096 + j4);
    float4 bo1 = *reinterpret_cast<const float4*>(bih + 6144 + j4);
    float4 bi2 = *reinterpret_cast<const float4*>(bhh + j4);
    float4 bf2 = *reinterpret_cast<const float4*>(bhh + 2048 + j4);
    float4 bg2 = *reinterpret_cast<const float4*>(bhh + 4096 + j4);
    float4 bo2 = *reinterpret_cast<const float4*>(bhh + 6144 + j4);

    gi.x += bi1.x + bi2.x; gi.y += bi1.y + bi2.y; gi.z += bi1.z + bi2.z; gi.w += bi1.w + bi2.w;
    gf.x += bf1.x + bf2.x; gf.y += bf1.y + bf2.y; gf.z += bf1.z + bf2.z; gf.w += bf1.w + bf2.w;
    gg.x += bg1.x + bg2.x; gg.y += bg1.y + bg2.y; gg.z += bg1.z + bg2.z; gg.w += bg1.w + bg2.w;
    go.x += bo1.x + bo2.x; go.y += bo1.y + bo2.y; go.z += bo1.z + bo2.z; go.w += bo1.w + bo2.w;

#pragma unroll
    for (int p = 0; p < NPARTS; ++p) {
        const float* hr = hW + (size_t)p * 524288 + (size_t)n * 8192;
        float4 hi = *reinterpret_cast<const float4*>(hr + j4);
        float4 hf = *reinterpret_cast<const float4*>(hr + 2048 + j4);
        float4 hg = *reinterpret_cast<const float4*>(hr + 4096 + j4);
        float4 ho = *reinterpret_cast<const float4*>(hr + 6144 + j4);
        gi.x += hi.x; gi.y += hi.y; gi.z += hi.z; gi.w += hi.w;
        gf.x += hf.x; gf.y += hf.y; gf.z += hf.z; gf.w += hf.w;
        gg.x += hg.x; gg.y += hg.y; gg.z += hg.z; gg.w += hg.w;
        go.x += ho.x; go.y += ho.y; go.z += ho.z; go.w += ho.w;
    }
    float4 cc;
    if (NPARTS == 0) { cc.x = cc.y = cc.z = cc.w = 0.f; }
    else             cc = *reinterpret_cast<const float4*>(c + (size_t)n * 2048 + j4);

    float cx = sigmf(gf.x) * cc.x + sigmf(gi.x) * tanhf_(gg.x);
    float cy = sigmf(gf.y) * cc.y + sigmf(gi.y) * tanhf_(gg.y);
    float cz = sigmf(gf.z) * cc.z + sigmf(gi.z) * tanhf_(gg.z);
    float cw = sigmf(gf.w) * cc.w + sigmf(gi.w) * tanhf_(gg.w);
    float hx = sigmf(go.x) * tanhf_(cx);
    float hy = sigmf(go.y) * tanhf_(cy);
    float hz = sigmf(go.z) * tanhf_(cz);
    float hw_ = sigmf(go.w) * tanhf_(cw);

    float4 co = {cx, cy, cz, cw};
    float4 ho_ = {hx, hy, hz, hw_};
    *reinterpret_cast<float4*>(c + (size_t)n * 2048 + j4) = co;
    *reinterpret_cast<float4*>(h + (size_t)n * 2048 + j4) = ho_;
    uint2 hp;
    hp.x = pack2(hx, hy);
    hp.y = pack2(hz, hw_);
    *reinterpret_cast<uint2*>(hbf + (size_t)n * 2048 + j4) = hp;
    if (hout) *reinterpret_cast<float4*>(hout + (size_t)n * 2048 + j4) = ho_;
}

// ---------------------------------------------------------------------------
// LayerNorm over last dim (2048). One block per row. Writes fp32 + bf16 copy.
// ---------------------------------------------------------------------------
__global__ __launch_bounds__(256) void layernorm_k(const float* __restrict__ x,
                                                   const float* __restrict__ g,
                                                   const float* __restrict__ b,
                                                   float* __restrict__ y,
                                                   u16* __restrict__ ybf) {
    int row = blockIdx.x;
    int tid = threadIdx.x, lane = tid & 63, wave = tid >> 6;
    const float* xr = x + (size_t)row * D2048;
    int j = tid * 8;
    float4 v1 = *reinterpret_cast<const float4*>(xr + j);
    float4 v2 = *reinterpret_cast<const float4*>(xr + j + 4);
    float s  = v1.x + v1.y + v1.z + v1.w + v2.x + v2.y + v2.z + v2.w;
    float s2 = v1.x * v1.x + v1.y * v1.y + v1.z * v1.z + v1.w * v1.w +
               v2.x * v2.x + v2.y * v2.y + v2.z * v2.z + v2.w * v2.w;
#pragma unroll
    for (int msk = 32; msk; msk >>= 1) {
        s  += __shfl_xor(s, msk, 64);
        s2 += __shfl_xor(s2, msk, 64);
    }
    __shared__ float red[4][2];
    if (lane == 0) { red[wave][0] = s; red[wave][1] = s2; }
    __syncthreads();
    s  = red[0][0] + red[1][0] + red[2][0] + red[3][0];
    s2 = red[0][1] + red[1][1] + red[2][1] + red[3][1];
    float mu  = s * (1.f / 2048.f);
    float var = s2 * (1.f / 2048.f) - mu * mu;
    float rs  = __frsqrt_rn(var + 1e-5f);

    float4 g1 = *reinterpret_cast<const float4*>(g + j);
    float4 g2 = *reinterpret_cast<const float4*>(g + j + 4);
    float4 b1 = *reinterpret_cast<const float4*>(b + j);
    float4 b2 = *reinterpret_cast<const float4*>(b + j + 4);
    float o[8];
    o[0] = (v1.x - mu) * rs * g1.x + b1.x;
    o[1] = (v1.y - mu) * rs * g1.y + b1.y;
    o[2] = (v1.z - mu) * rs * g1.z + b1.z;
    o[3] = (v1.w - mu) * rs * g1.w + b1.w;
    o[4] = (v2.x - mu) * rs * g2.x + b2.x;
    o[5] = (v2.y - mu) * rs * g2.y + b2.y;
    o[6] = (v2.z - mu) * rs * g2.z + b2.z;
    o[7] = (v2.w - mu) * rs * g2.w + b2.w;
    float4 o1 = {o[0], o[1], o[2], o[3]};
    float4 o2 = {o[4], o[5], o[6], o[7]};
    float* yr = y + (size_t)row * D2048;
    *reinterpret_cast<float4*>(yr + j)     = o1;
    *reinterpret_cast<float4*>(yr + j + 4) = o2;
    uint4 p;
    p.x = pack2(o[0], o[1]);
    p.y = pack2(o[2], o[3]);
    p.z = pack2(o[4], o[5]);
    p.w = pack2(o[6], o[7]);
    *reinterpret_cast<uint4*>(ybf + (size_t)row * D2048 + j) = p;
}

// ---------------------------------------------------------------------------
static inline void launch_gemm(hipStream_t s, const u16* A, int lda, const u16* B,
                               const float* bias, void* C, int M, int N, int K,
                               bool outbf) {
    dim3 grid(N / 128, M / 128);
    if (outbf)
        gemm_bt<true, true><<<grid, 256, 0, s>>>(A, lda, B, bias, C, M, N, K);
    else
        gemm_bt<false, false><<<grid, 256, 0, s>>>(A, lda, B, nullptr, C, M, N, K);
}

static inline void launch_cvt(hipStream_t s, const float* in, u16* out, int nelem) {
    int n4 = nelem >> 2;
    cvt_f32_bf16<<<(n4 + 255) / 256, 256, 0, s>>>(in, out, n4);
}

extern "C" void kernel_launch(void* const* d_in, const int* in_sizes, int n_in,
                              void* d_out, int out_size, void* d_ws, size_t ws_size,
                              hipStream_t stream) {
    const float* fc      = (const float*)d_in[0];
    const float* nsa_Wq  = (const float*)d_in[1];
    const float* nsa_Wk  = (const float*)d_in[2];
    const float* nsa_Wv  = (const float*)d_in[3];
    const float* nsa_bq  = (const float*)d_in[4];
    const float* nsa_bk  = (const float*)d_in[5];
    const float* nsa_bv  = (const float*)d_in[6];
    const float* nsa_Wih = (const float*)d_in[7];
    const float* nsa_Whh = (const float*)d_in[8];
    const float* nsa_bih = (const float*)d_in[9];
    const float* nsa_bhh = (const float*)d_in[10];
    const float* sa_Wq   = (const float*)d_in[11];
    const float* sa_Wk   = (const float*)d_in[12];
    const float* sa_Wv   = (const float*)d_in[13];
    const float* sa_bq   = (const float*)d_in[14];
    const float* sa_bk   = (const float*)d_in[15];
    const float* sa_bv   = (const float*)d_in[16];
    const float* sa_Wih  = (const float*)d_in[17];
    const float* sa_Whh  = (const float*)d_in[18];
    const float* sa_bih  = (const float*)d_in[19];
    const float* sa_bhh  = (const float*)d_in[20];
    const float* ln_g    = (const float*)d_in[21];
    const float* ln_b    = (const float*)d_in[22];

    float* outF   = (float*)d_out;
    float* out_sa = outF;            // (64,2048)
    float* out_ln = outF + 131072;   // (64,16,2048)

    char* W = (char*)d_ws;
    // persistent bf16 weight slots (sa QKV/Wih alias dead nsa slots mid-stream)
    u16* W_q   = (u16*)(W + 0);          // 2048x2048 (nsa_Wq, then sa_Wq)
    u16* W_k   = (u16*)(W + 8388608);
    u16* W_v   = (u16*)(W + 16777216);
    u16* W_ih  = (u16*)(W + 25165824);   // 8192x2048 (nsa_Wih, then sa_Wih)
    u16* W_hh1 = (u16*)(W + 58720256);   // nsa_Whh
    u16* W_hh2 = (u16*)(W + 92274688);   // sa_Whh
    u16*   Xbf  = (u16*)(W + 125829120); // 1280x2048 bf16; lnbf alias
    u16*   q0   = (u16*)(W + 131072000);
    u16*   k0   = (u16*)(W + 136314880);
    u16*   v0   = (u16*)(W + 141557760);
    u16*   att1 = (u16*)(W + 146800640); // 5120x2048 bf16; att2 alias
    float* xg   = (float*)(W + 167772160); // 1024x8192 f32 (reused per nsa step; xg2)
    float* hW   = (float*)(W + 201326592); // 1024x8192 f32; also 4 skinny partials
    float* h1   = (float*)(W + 234881024); // 1024x2048 f32
    float* c1   = (float*)(W + 243269632);
    u16*   h1bf = (u16*)(W + 251658240);   // 1024x2048 bf16
    // end: 255852544 bytes (~244 MiB)

    u16* lnbf = Xbf;
    u16 *q2 = q0, *k2 = k0, *v2 = v0;
    u16* att2 = att1;

    // 0) convert fc + nsa weights + sa_Whh to bf16
    launch_cvt(stream, fc,      Xbf,   2621440);
    launch_cvt(stream, nsa_Wq,  W_q,   4194304);
    launch_cvt(stream, nsa_Wk,  W_k,   4194304);
    launch_cvt(stream, nsa_Wv,  W_v,   4194304);
    launch_cvt(stream, nsa_Wih, W_ih,  16777216);
    launch_cvt(stream, nsa_Whh, W_hh1, 16777216);
    launch_cvt(stream, sa_Whh,  W_hh2, 16777216);

    // 1) nsa QKV on the 1280 unique rows
    launch_gemm(stream, Xbf, 2048, W_q, nsa_bq, q0, 1280, 2048, 2048, true);
    launch_gemm(stream, Xbf, 2048, W_k, nsa_bk, k0, 1280, 2048, 2048, true);
    launch_gemm(stream, Xbf, 2048, W_v, nsa_bv, v0, 1280, 2048, 2048, true);

    // 2) windowed attention
    attn_win5<<<1024, 256, 0, stream>>>(q0, k0, v0, att1);

    // 3+4) nsa LSTM, 5 steps; xg computed per step with lda=5*2048 row gather
    for (int t = 0; t < 5; ++t) {
        launch_gemm(stream, att1 + t * 2048, 5 * 2048, W_ih, nullptr, xg,
                    1024, 8192, 2048, false);
        if (t == 0) {
            lstm_gate<0><<<2048, 256, 0, stream>>>(xg, 8192, nullptr, nsa_bih, nsa_bhh,
                                                   c1, h1, h1bf, nullptr, 1024);
        } else {
            launch_gemm(stream, h1bf, 2048, W_hh1, nullptr, hW, 1024, 8192, 2048, false);
            lstm_gate<1><<<2048, 256, 0, stream>>>(xg, 8192, hW, nsa_bih, nsa_bhh,
                                                   c1, h1, h1bf, nullptr, 1024);
        }
    }

    // 5) LayerNorm -> output 1 (fp32) + bf16 copy for stage 2
    layernorm_k<<<1024, 256, 0, stream>>>(h1, ln_g, ln_b, out_ln, lnbf);

    // 5b) convert sa single-use weights into the (now dead) nsa slots
    launch_cvt(stream, sa_Wq,  W_q,  4194304);
    launch_cvt(stream, sa_Wk,  W_k,  4194304);
    launch_cvt(stream, sa_Wv,  W_v,  4194304);
    launch_cvt(stream, sa_Wih, W_ih, 16777216);

    // 6) sa QKV
    launch_gemm(stream, lnbf, 2048, W_q, sa_bq, q2, 1024, 2048, 2048, true);
    launch_gemm(stream, lnbf, 2048, W_k, sa_bk, k2, 1024, 2048, 2048, true);
    launch_gemm(stream, lnbf, 2048, W_v, sa_bv, v2, 1024, 2048, 2048, true);

    // 7) seq-16 attention
    attn_seq16<<<1024, 256, 0, stream>>>(q2, k2, v2, att2);

    // 8) xg2 = att2 @ saWih^T (all 16 steps at once; gate reads strided)
    launch_gemm(stream, att2, 2048, W_ih, nullptr, xg, 1024, 8192, 2048, false);

    // 9) sa LSTM over 16 steps (rows = 64); recurrent GEMM = skinny split-K=4
    lstm_gate<0><<<128, 256, 0, stream>>>(xg, 131072, nullptr, sa_bih, sa_bhh,
                                          c1, h1, h1bf, nullptr, 64);
    for (int t = 1; t < 16; ++t) {
        gemm_skinny64<<<dim3(64, 4), 256, 0, stream>>>(h1bf, W_hh2, hW, 8192, 2048);
        lstm_gate<4><<<128, 256, 0, stream>>>(xg + (size_t)t * 8192, 131072, hW,
                                              sa_bih, sa_bhh, c1, h1, h1bf,
                                              (t == 15) ? out_sa : nullptr, 64);
    }
}

// Round 3
// 1077.366 us; speedup vs baseline: 1.8104x; 1.2176x over previous
//
#include <hip/hip_runtime.h>
#include <hip/hip_bf16.h>

typedef unsigned int  u32;
typedef unsigned short u16;

typedef __bf16 bf16x8 __attribute__((ext_vector_type(8)));
typedef float  f32x4  __attribute__((ext_vector_type(4)));

#define D2048 2048
#define SCALE 0.022097086912079612f

__device__ __forceinline__ u32 f2bfbits(float f) {
    u32 u = __float_as_uint(f);
    return (u + 0x7FFFu + ((u >> 16) & 1u)) >> 16;   // RNE
}
__device__ __forceinline__ u32 pack2(float a, float b) {
    return f2bfbits(a) | (f2bfbits(b) << 16);
}
__device__ __forceinline__ float bf2f(u32 h) {
    return __uint_as_float(h << 16);
}
__device__ __forceinline__ void unpack8(uint4 v, float* f) {
    f[0] = bf2f(v.x & 0xFFFFu); f[1] = bf2f(v.x >> 16);
    f[2] = bf2f(v.y & 0xFFFFu); f[3] = bf2f(v.y >> 16);
    f[4] = bf2f(v.z & 0xFFFFu); f[5] = bf2f(v.z >> 16);
    f[6] = bf2f(v.w & 0xFFFFu); f[7] = bf2f(v.w >> 16);
}
__device__ __forceinline__ float sigmf(float x) { return 1.f / (1.f + __expf(-x)); }
__device__ __forceinline__ float tanhf_(float x) {
    x = fminf(15.f, fmaxf(-15.f, x));
    float e = __expf(2.f * x);
    return (e - 1.f) / (e + 1.f);
}

// async global->LDS, 16B per lane. LDS dest: wave-uniform base + lane*16B.
__device__ __forceinline__ void gload_lds16(const u16* g, u16* l) {
    __builtin_amdgcn_global_load_lds(
        (const __attribute__((address_space(1))) unsigned int*)g,
        (__attribute__((address_space(3))) unsigned int*)l,
        16, 0, 0);
}

// ---------------------------------------------------------------------------
// Multi-segment fp32 -> bf16 conversion (grid-stride per segment)
// ---------------------------------------------------------------------------
struct CvtArgs {
    const float* src[8];
    u16*         dst[8];
    int          n4[8];
    int          nseg;
};
__global__ __launch_bounds__(256) void cvt_multi(CvtArgs a) {
    int stride = gridDim.x * 256;
    for (int s = 0; s < a.nseg; ++s) {
        const float4* S = reinterpret_cast<const float4*>(a.src[s]);
        uint2*        D = reinterpret_cast<uint2*>(a.dst[s]);
        int n4 = a.n4[s];
        for (int i = blockIdx.x * 256 + threadIdx.x; i < n4; i += stride) {
            float4 v = S[i];
            uint2 p;
            p.x = pack2(v.x, v.y);
            p.y = pack2(v.z, v.w);
            D[i] = p;
        }
    }
}

// ---------------------------------------------------------------------------
// GEMM: C[M][N] = A[M][K](bf16, row stride lda) * B[N][K](bf16)^T (+bias)
// 128x128 tile, BK=64, 4 waves, global_load_lds width-16, DOUBLE-BUFFERED
// 2-phase pipeline: stage(t+1) issued before compute(t); raw s_barrier +
// counted vmcnt(8) so next-tile loads stay in flight across the barrier.
// QKV3: blockIdx.z selects one of 3 B/bias/output panels (shared A).
// Requires M%128==0, N%128==0, K%64==0.
// ---------------------------------------------------------------------------
template <bool QKV3, bool HAS_BIAS, bool OUT_BF16>
__global__ __launch_bounds__(256) void gemm_bt(const u16* __restrict__ A, int lda,
                                               const u16* __restrict__ B0,
                                               const u16* __restrict__ B1,
                                               const u16* __restrict__ B2,
                                               const float* __restrict__ bias0,
                                               const float* __restrict__ bias1,
                                               const float* __restrict__ bias2,
                                               void* __restrict__ Cout,
                                               size_t zCstride,
                                               int M, int N, int K) {
    __shared__ u16 Abuf[2][128 * 64];
    __shared__ u16 Bbuf[2][128 * 64];

    const int tid  = threadIdx.x;
    const int lane = tid & 63;
    const int wave = tid >> 6;
    const int wr   = (wave >> 1) * 64;
    const int wc   = (wave & 1) * 64;
    const int rowBase = blockIdx.y * 128;
    const int colBase = blockIdx.x * 128;
    const int l15 = lane & 15, l4 = lane >> 4;
    const int srow = lane >> 3;        // 0..7
    const int scol = (lane & 7) * 8;   // bf16 col within BK

    const u16* B = B0;
    const float* bias = bias0;
    void* C = Cout;
    if (QKV3) {
        int z = blockIdx.z;
        B    = (z == 0) ? B0 : ((z == 1) ? B1 : B2);
        bias = (z == 0) ? bias0 : ((z == 1) ? bias1 : bias2);
        C    = OUT_BF16 ? (void*)((u16*)Cout + (size_t)z * zCstride)
                        : (void*)((float*)Cout + (size_t)z * zCstride);
    }

    const u16* ga = A + (size_t)(rowBase + wave * 32 + srow) * lda + scol;
    const u16* gb = B + (size_t)(colBase + wave * 32 + srow) * K + scol;
    const int ldsOff = (wave * 32) * 64;

    f32x4 acc[4][4];
#pragma unroll
    for (int i = 0; i < 4; i++)
#pragma unroll
        for (int j = 0; j < 4; j++) acc[i][j] = f32x4{0.f, 0.f, 0.f, 0.f};

    const int nt = K >> 6;

    // prologue: stage tile 0 into buffer 0
#pragma unroll
    for (int i = 0; i < 4; ++i) {
        gload_lds16(ga + (size_t)(i * 8) * lda, &Abuf[0][ldsOff + i * 8 * 64]);
        gload_lds16(gb + (size_t)(i * 8) * K,   &Bbuf[0][ldsOff + i * 8 * 64]);
    }

    for (int t = 0; t < nt; ++t) {
        const int cur = t & 1;
        if (t + 1 < nt) {
            const int k1 = (t + 1) << 6;
#pragma unroll
            for (int i = 0; i < 4; ++i) {
                gload_lds16(ga + (size_t)(i * 8) * lda + k1,
                            &Abuf[cur ^ 1][ldsOff + i * 8 * 64]);
                gload_lds16(gb + (size_t)(i * 8) * K + k1,
                            &Bbuf[cur ^ 1][ldsOff + i * 8 * 64]);
            }
            asm volatile("s_waitcnt vmcnt(8)" ::: "memory");
        } else {
            asm volatile("s_waitcnt vmcnt(0)" ::: "memory");
        }
        __builtin_amdgcn_s_barrier();
        __builtin_amdgcn_sched_barrier(0);
#pragma unroll
        for (int kk = 0; kk < 2; ++kk) {
            bf16x8 af[4], bfr[4];
#pragma unroll
            for (int i = 0; i < 4; i++) {
                af[i]  = *reinterpret_cast<const bf16x8*>(
                    &Abuf[cur][(wr + i * 16 + l15) * 64 + kk * 32 + l4 * 8]);
                bfr[i] = *reinterpret_cast<const bf16x8*>(
                    &Bbuf[cur][(wc + i * 16 + l15) * 64 + kk * 32 + l4 * 8]);
            }
#pragma unroll
            for (int i = 0; i < 4; i++)
#pragma unroll
                for (int j = 0; j < 4; j++)
                    acc[i][j] = __builtin_amdgcn_mfma_f32_16x16x32_bf16(af[i], bfr[j],
                                                                        acc[i][j], 0, 0, 0);
        }
        __builtin_amdgcn_sched_barrier(0);
        __builtin_amdgcn_s_barrier();
    }

    // C/D layout: col=lane&15, row=(lane>>4)*4+reg
#pragma unroll
    for (int i = 0; i < 4; i++) {
        int row0 = rowBase + wr + i * 16 + l4 * 4;
#pragma unroll
        for (int j = 0; j < 4; j++) {
            int col = colBase + wc + j * 16 + l15;
            float bv = HAS_BIAS ? bias[col] : 0.f;
#pragma unroll
            for (int rr = 0; rr < 4; rr++) {
                float val = acc[i][j][rr] + bv;
                if (OUT_BF16)
                    ((u16*)C)[(size_t)(row0 + rr) * N + col] = (u16)f2bfbits(val);
                else
                    ((float*)C)[(size_t)(row0 + rr) * N + col] = val;
            }
        }
    }
}

// ---------------------------------------------------------------------------
// Skinny GEMM for the sa recurrence: C_part[kp] = A[64][Kseg] * B[N][Kseg]^T
// Tile 64x128, 4 waves, split-K=4 over gridDim.y, double-buffered pipeline.
// ---------------------------------------------------------------------------
__global__ __launch_bounds__(256) void gemm_skinny64(const u16* __restrict__ A,
                                                     const u16* __restrict__ B,
                                                     float* __restrict__ part,
                                                     int N, int K) {
    __shared__ u16 Abuf[2][64 * 64];
    __shared__ u16 Bbuf[2][128 * 64];
    const int tid = threadIdx.x, lane = tid & 63, wave = tid >> 6;
    const int colBase = blockIdx.x * 128;
    const int kp = blockIdx.y;
    const int kseg = K >> 2;
    const int kBeg = kp * kseg;
    const int l15 = lane & 15, l4 = lane >> 4;
    const int srow = lane >> 3, scol = (lane & 7) * 8;

    const u16* ga = A + (size_t)(wave * 16 + srow) * K + scol + kBeg;
    const u16* gb = B + (size_t)(colBase + wave * 32 + srow) * K + scol + kBeg;
    const int laOff = (wave * 16) * 64;
    const int lbOff = (wave * 32) * 64;

    f32x4 acc[4][2];
#pragma unroll
    for (int i = 0; i < 4; i++)
#pragma unroll
        for (int j = 0; j < 2; j++) acc[i][j] = f32x4{0.f, 0.f, 0.f, 0.f};

    const int nt = kseg >> 6;

#pragma unroll
    for (int i = 0; i < 2; ++i)
        gload_lds16(ga + (size_t)(i * 8) * K, &Abuf[0][laOff + i * 8 * 64]);
#pragma unroll
    for (int i = 0; i < 4; ++i)
        gload_lds16(gb + (size_t)(i * 8) * K, &Bbuf[0][lbOff + i * 8 * 64]);

    for (int t = 0; t < nt; ++t) {
        const int cur = t & 1;
        if (t + 1 < nt) {
            const int k1 = (t + 1) << 6;
#pragma unroll
            for (int i = 0; i < 2; ++i)
                gload_lds16(ga + (size_t)(i * 8) * K + k1, &Abuf[cur ^ 1][laOff + i * 8 * 64]);
#pragma unroll
            for (int i = 0; i < 4; ++i)
                gload_lds16(gb + (size_t)(i * 8) * K + k1, &Bbuf[cur ^ 1][lbOff + i * 8 * 64]);
            asm volatile("s_waitcnt vmcnt(6)" ::: "memory");
        } else {
            asm volatile("s_waitcnt vmcnt(0)" ::: "memory");
        }
        __builtin_amdgcn_s_barrier();
        __builtin_amdgcn_sched_barrier(0);
#pragma unroll
        for (int kk = 0; kk < 2; ++kk) {
            bf16x8 af[4], bfr[2];
#pragma unroll
            for (int i = 0; i < 4; i++)
                af[i] = *reinterpret_cast<const bf16x8*>(
                    &Abuf[cur][(i * 16 + l15) * 64 + kk * 32 + l4 * 8]);
#pragma unroll
            for (int j = 0; j < 2; j++)
                bfr[j] = *reinterpret_cast<const bf16x8*>(
                    &Bbuf[cur][(wave * 32 + j * 16 + l15) * 64 + kk * 32 + l4 * 8]);
#pragma unroll
            for (int i = 0; i < 4; i++)
#pragma unroll
                for (int j = 0; j < 2; j++)
                    acc[i][j] = __builtin_amdgcn_mfma_f32_16x16x32_bf16(af[i], bfr[j],
                                                                        acc[i][j], 0, 0, 0);
        }
        __builtin_amdgcn_sched_barrier(0);
        __builtin_amdgcn_s_barrier();
    }

    float* cp = part + (size_t)kp * 64 * N;
#pragma unroll
    for (int i = 0; i < 4; i++) {
        int row0 = i * 16 + l4 * 4;
#pragma unroll
        for (int j = 0; j < 2; j++) {
            int col = colBase + wave * 32 + j * 16 + l15;
#pragma unroll
            for (int rr = 0; rr < 4; rr++)
                cp[(size_t)(row0 + rr) * N + col] = acc[i][j][rr];
        }
    }
}

// ---------------------------------------------------------------------------
// Attention over 5-windows. One block per window n = b*16+t.
// ---------------------------------------------------------------------------
__global__ __launch_bounds__(256) void attn_win5(const u16* __restrict__ q0,
                                                 const u16* __restrict__ k0,
                                                 const u16* __restrict__ v0,
                                                 u16* __restrict__ att) {
    int n = blockIdx.x;  // 0..1023
    int b = n >> 4, t = n & 15;
    int tid = threadIdx.x, lane = tid & 63, wave = tid >> 6;
    int d0 = tid * 8;
    size_t base = (size_t)(b * 20 + t) * D2048;

    float qv[5][8];
#pragma unroll
    for (int i = 0; i < 5; i++) {
        uint4 v = *reinterpret_cast<const uint4*>(q0 + base + (size_t)i * D2048 + d0);
        unpack8(v, qv[i]);
    }
    float part[25];
#pragma unroll
    for (int p = 0; p < 25; p++) part[p] = 0.f;
#pragma unroll
    for (int m = 0; m < 5; m++) {
        float kv[8];
        uint4 v = *reinterpret_cast<const uint4*>(k0 + base + (size_t)m * D2048 + d0);
        unpack8(v, kv);
#pragma unroll
        for (int l = 0; l < 5; l++)
#pragma unroll
            for (int j = 0; j < 8; j++) part[l * 5 + m] += qv[l][j] * kv[j];
    }
#pragma unroll
    for (int p = 0; p < 25; p++) {
        float s = part[p];
#pragma unroll
        for (int msk = 32; msk; msk >>= 1) s += __shfl_xor(s, msk, 64);
        part[p] = s;
    }
    __shared__ float wred[4][25];
    __shared__ float wmat[25];
    if (lane == 0) {
#pragma unroll
        for (int p = 0; p < 25; p++) wred[wave][p] = part[p];
    }
    __syncthreads();
    if (tid < 5) {
        int l = tid;
        float dv[5], mx = -1e30f;
#pragma unroll
        for (int m = 0; m < 5; m++) {
            dv[m] = (wred[0][l * 5 + m] + wred[1][l * 5 + m] + wred[2][l * 5 + m] +
                     wred[3][l * 5 + m]) * SCALE;
            mx = fmaxf(mx, dv[m]);
        }
        float ssum = 0.f;
#pragma unroll
        for (int m = 0; m < 5; m++) { dv[m] = __expf(dv[m] - mx); ssum += dv[m]; }
        float inv = 1.f / ssum;
#pragma unroll
        for (int m = 0; m < 5; m++) wmat[l * 5 + m] = dv[m] * inv;
    }
    __syncthreads();

    float oacc[5][8];
#pragma unroll
    for (int l = 0; l < 5; l++)
#pragma unroll
        for (int j = 0; j < 8; j++) oacc[l][j] = 0.f;
#pragma unroll
    for (int m = 0; m < 5; m++) {
        float vv[8];
        uint4 v = *reinterpret_cast<const uint4*>(v0 + base + (size_t)m * D2048 + d0);
        unpack8(v, vv);
#pragma unroll
        for (int l = 0; l < 5; l++) {
            float w = wmat[l * 5 + m];
#pragma unroll
            for (int j = 0; j < 8; j++) oacc[l][j] += w * vv[j];
        }
    }
#pragma unroll
    for (int l = 0; l < 5; l++) {
        uint4 p;
        p.x = pack2(oacc[l][0], oacc[l][1]);
        p.y = pack2(oacc[l][2], oacc[l][3]);
        p.z = pack2(oacc[l][4], oacc[l][5]);
        p.w = pack2(oacc[l][6], oacc[l][7]);
        *reinterpret_cast<uint4*>(att + (size_t)(n * 5 + l) * D2048 + d0) = p;
    }
}

// ---------------------------------------------------------------------------
// Attention over seq-16. One block per output row r = b*16 + l.
// ---------------------------------------------------------------------------
__global__ __launch_bounds__(256) void attn_seq16(const u16* __restrict__ q2,
                                                  const u16* __restrict__ k2,
                                                  const u16* __restrict__ v2,
                                                  u16* __restrict__ att2) {
    int r = blockIdx.x;  // 0..1023
    int b = r >> 4;
    int tid = threadIdx.x, lane = tid & 63, wave = tid >> 6;
    int d0 = tid * 8;
    size_t kbase = (size_t)b * 16 * D2048;

    float qv[8];
    {
        uint4 v = *reinterpret_cast<const uint4*>(q2 + (size_t)r * D2048 + d0);
        unpack8(v, qv);
    }
    float part[16];
#pragma unroll
    for (int m = 0; m < 16; m++) part[m] = 0.f;
#pragma unroll
    for (int m = 0; m < 16; m++) {
        float kv[8];
        uint4 v = *reinterpret_cast<const uint4*>(k2 + kbase + (size_t)m * D2048 + d0);
        unpack8(v, kv);
#pragma unroll
        for (int j = 0; j < 8; j++) part[m] += qv[j] * kv[j];
    }
#pragma unroll
    for (int m = 0; m < 16; m++) {
        float s = part[m];
#pragma unroll
        for (int msk = 32; msk; msk >>= 1) s += __shfl_xor(s, msk, 64);
        part[m] = s;
    }
    __shared__ float wred[4][16];
    __shared__ float wmat[16];
    if (lane == 0) {
#pragma unroll
        for (int m = 0; m < 16; m++) wred[wave][m] = part[m];
    }
    __syncthreads();
    if (tid == 0) {
        float dv[16], mx = -1e30f;
#pragma unroll
        for (int m = 0; m < 16; m++) {
            dv[m] = (wred[0][m] + wred[1][m] + wred[2][m] + wred[3][m]) * SCALE;
            mx = fmaxf(mx, dv[m]);
        }
        float ssum = 0.f;
#pragma unroll
        for (int m = 0; m < 16; m++) { dv[m] = __expf(dv[m] - mx); ssum += dv[m]; }
        float inv = 1.f / ssum;
#pragma unroll
        for (int m = 0; m < 16; m++) wmat[m] = dv[m] * inv;
    }
    __syncthreads();

    float oacc[8];
#pragma unroll
    for (int j = 0; j < 8; j++) oacc[j] = 0.f;
#pragma unroll
    for (int m = 0; m < 16; m++) {
        float vv[8];
        uint4 v = *reinterpret_cast<const uint4*>(v2 + kbase + (size_t)m * D2048 + d0);
        unpack8(v, vv);
        float w = wmat[m];
#pragma unroll
        for (int j = 0; j < 8; j++) oacc[j] += w * vv[j];
    }
    uint4 p;
    p.x = pack2(oacc[0], oacc[1]);
    p.y = pack2(oacc[2], oacc[3]);
    p.z = pack2(oacc[4], oacc[5]);
    p.w = pack2(oacc[6], oacc[7]);
    *reinterpret_cast<uint4*>(att2 + (size_t)r * D2048 + d0) = p;
}

// ---------------------------------------------------------------------------
// LSTM gate update. xg is bf16 (row stride xg_stride elems). NPARTS==0:
// first step (c=0, no hW). NPARTS>=1: sum NPARTS fp32 partial hW buffers
// (partial stride 64*8192 for split-K; NPARTS==1 reads one full buffer).
// ---------------------------------------------------------------------------
template <int NPARTS>
__global__ __launch_bounds__(256) void lstm_gate(const u16* __restrict__ xg,
                                                 int xg_stride,
                                                 const float* __restrict__ hW,
                                                 const float* __restrict__ bih,
                                                 const float* __restrict__ bhh,
                                                 float* __restrict__ c,
                                                 float* __restrict__ h,
                                                 u16* __restrict__ hbf,
                                                 float* __restrict__ hout,
                                                 int rows) {
    int idx = blockIdx.x * 256 + threadIdx.x;
    int total = rows * 512;
    if (idx >= total) return;
    int n  = idx >> 9;
    int j4 = (idx & 511) * 4;

    const u16* xr = xg + (size_t)n * xg_stride + j4;
    float4 gi, gf, gg, go;
    {
        uint2 ri = *reinterpret_cast<const uint2*>(xr);
        uint2 rf = *reinterpret_cast<const uint2*>(xr + 2048);
        uint2 rg = *reinterpret_cast<const uint2*>(xr + 4096);
        uint2 ro = *reinterpret_cast<const uint2*>(xr + 6144);
        gi = {bf2f(ri.x & 0xFFFFu), bf2f(ri.x >> 16), bf2f(ri.y & 0xFFFFu), bf2f(ri.y >> 16)};
        gf = {bf2f(rf.x & 0xFFFFu), bf2f(rf.x >> 16), bf2f(rf.y & 0xFFFFu), bf2f(rf.y >> 16)};
        gg = {bf2f(rg.x & 0xFFFFu), bf2f(rg.x >> 16), bf2f(rg.y & 0xFFFFu), bf2f(rg.y >> 16)};
        go = {bf2f(ro.x & 0xFFFFu), bf2f(ro.x >> 16), bf2f(ro.y & 0xFFFFu), bf2f(ro.y >> 16)};
    }

    float4 bi1 = *reinterpret_cast<const float4*>(bih + j4);
    float4 bf1 = *reinterpret_cast<const float4*>(bih + 2048 + j4);
    float4 bg1 = *reinterpret_cast<const float4*>(bih + 4096 + j4);
    float4 bo1 = *reinterpret_cast<const float4*>(bih + 6144 + j4);
    float4 bi2 = *reinterpret_cast<const float4*>(bhh + j4);
    float4 bf2_ = *reinterpret_cast<const float4*>(bhh + 2048 + j4);
    float4 bg2 = *reinterpret_cast<const float4*>(bhh + 4096 + j4);
    float4 bo2 = *reinterpret_cast<const float4*>(bhh + 6144 + j4);

    gi.x += bi1.x + bi2.x; gi.y += bi1.y + bi2.y; gi.z += bi1.z + bi2.z; gi.w += bi1.w + bi2.w;
    gf.x += bf1.x + bf2_.x; gf.y += bf1.y + bf2_.y; gf.z += bf1.z + bf2_.z; gf.w += bf1.w + bf2_.w;
    gg.x += bg1.x + bg2.x; gg.y += bg1.y + bg2.y; gg.z += bg1.z + bg2.z; gg.w += bg1.w + bg2.w;
    go.x += bo1.x + bo2.x; go.y += bo1.y + bo2.y; go.z += bo1.z + bo2.z; go.w += bo1.w + bo2.w;

#pragma unroll
    for (int p = 0; p < NPARTS; ++p) {
        const float* hr = hW + (size_t)p * 524288 + (size_t)n * 8192;
        float4 hi = *reinterpret_cast<const float4*>(hr + j4);
        float4 hf = *reinterpret_cast<const float4*>(hr + 2048 + j4);
        float4 hg = *reinterpret_cast<const float4*>(hr + 4096 + j4);
        float4 ho = *reinterpret_cast<const float4*>(hr + 6144 + j4);
        gi.x += hi.x; gi.y += hi.y; gi.z += hi.z; gi.w += hi.w;
        gf.x += hf.x; gf.y += hf.y; gf.z += hf.z; gf.w += hf.w;
        gg.x += hg.x; gg.y += hg.y; gg.z += hg.z; gg.w += hg.w;
        go.x += ho.x; go.y += ho.y; go.z += ho.z; go.w += ho.w;
    }
    float4 cc;
    if (NPARTS == 0) { cc.x = cc.y = cc.z = cc.w = 0.f; }
    else             cc = *reinterpret_cast<const float4*>(c + (size_t)n * 2048 + j4);

    float cx = sigmf(gf.x) * cc.x + sigmf(gi.x) * tanhf_(gg.x);
    float cy = sigmf(gf.y) * cc.y + sigmf(gi.y) * tanhf_(gg.y);
    float cz = sigmf(gf.z) * cc.z + sigmf(gi.z) * tanhf_(gg.z);
    float cw = sigmf(gf.w) * cc.w + sigmf(gi.w) * tanhf_(gg.w);
    float hx = sigmf(go.x) * tanhf_(cx);
    float hy = sigmf(go.y) * tanhf_(cy);
    float hz = sigmf(go.z) * tanhf_(cz);
    float hw_ = sigmf(go.w) * tanhf_(cw);

    float4 co = {cx, cy, cz, cw};
    float4 ho_ = {hx, hy, hz, hw_};
    *reinterpret_cast<float4*>(c + (size_t)n * 2048 + j4) = co;
    *reinterpret_cast<float4*>(h + (size_t)n * 2048 + j4) = ho_;
    uint2 hp;
    hp.x = pack2(hx, hy);
    hp.y = pack2(hz, hw_);
    *reinterpret_cast<uint2*>(hbf + (size_t)n * 2048 + j4) = hp;
    if (hout) *reinterpret_cast<float4*>(hout + (size_t)n * 2048 + j4) = ho_;
}

// ---------------------------------------------------------------------------
// LayerNorm over last dim (2048). One block per row. Writes fp32 + bf16 copy.
// ---------------------------------------------------------------------------
__global__ __launch_bounds__(256) void layernorm_k(const float* __restrict__ x,
                                                   const float* __restrict__ g,
                                                   const float* __restrict__ b,
                                                   float* __restrict__ y,
                                                   u16* __restrict__ ybf) {
    int row = blockIdx.x;
    int tid = threadIdx.x, lane = tid & 63, wave = tid >> 6;
    const float* xr = x + (size_t)row * D2048;
    int j = tid * 8;
    float4 v1 = *reinterpret_cast<const float4*>(xr + j);
    float4 v2 = *reinterpret_cast<const float4*>(xr + j + 4);
    float s  = v1.x + v1.y + v1.z + v1.w + v2.x + v2.y + v2.z + v2.w;
    float s2 = v1.x * v1.x + v1.y * v1.y + v1.z * v1.z + v1.w * v1.w +
               v2.x * v2.x + v2.y * v2.y + v2.z * v2.z + v2.w * v2.w;
#pragma unroll
    for (int msk = 32; msk; msk >>= 1) {
        s  += __shfl_xor(s, msk, 64);
        s2 += __shfl_xor(s2, msk, 64);
    }
    __shared__ float red[4][2];
    if (lane == 0) { red[wave][0] = s; red[wave][1] = s2; }
    __syncthreads();
    s  = red[0][0] + red[1][0] + red[2][0] + red[3][0];
    s2 = red[0][1] + red[1][1] + red[2][1] + red[3][1];
    float mu  = s * (1.f / 2048.f);
    float var = s2 * (1.f / 2048.f) - mu * mu;
    float rs  = __frsqrt_rn(var + 1e-5f);

    float4 g1 = *reinterpret_cast<const float4*>(g + j);
    float4 g2 = *reinterpret_cast<const float4*>(g + j + 4);
    float4 b1 = *reinterpret_cast<const float4*>(b + j);
    float4 b2 = *reinterpret_cast<const float4*>(b + j + 4);
    float o[8];
    o[0] = (v1.x - mu) * rs * g1.x + b1.x;
    o[1] = (v1.y - mu) * rs * g1.y + b1.y;
    o[2] = (v1.z - mu) * rs * g1.z + b1.z;
    o[3] = (v1.w - mu) * rs * g1.w + b1.w;
    o[4] = (v2.x - mu) * rs * g2.x + b2.x;
    o[5] = (v2.y - mu) * rs * g2.y + b2.y;
    o[6] = (v2.z - mu) * rs * g2.z + b2.z;
    o[7] = (v2.w - mu) * rs * g2.w + b2.w;
    float4 o1 = {o[0], o[1], o[2], o[3]};
    float4 o2 = {o[4], o[5], o[6], o[7]};
    float* yr = y + (size_t)row * D2048;
    *reinterpret_cast<float4*>(yr + j)     = o1;
    *reinterpret_cast<float4*>(yr + j + 4) = o2;
    uint4 p;
    p.x = pack2(o[0], o[1]);
    p.y = pack2(o[2], o[3]);
    p.z = pack2(o[4], o[5]);
    p.w = pack2(o[6], o[7]);
    *reinterpret_cast<uint4*>(ybf + (size_t)row * D2048 + j) = p;
}

// ---------------------------------------------------------------------------
static inline void launch_gemm1(hipStream_t s, const u16* A, int lda, const u16* B,
                                void* C, int M, int N, int K, bool outbf) {
    dim3 grid(N / 128, M / 128);
    if (outbf)
        gemm_bt<false, false, true><<<grid, 256, 0, s>>>(A, lda, B, B, B,
            nullptr, nullptr, nullptr, C, 0, M, N, K);
    else
        gemm_bt<false, false, false><<<grid, 256, 0, s>>>(A, lda, B, B, B,
            nullptr, nullptr, nullptr, C, 0, M, N, K);
}

static inline void launch_qkv(hipStream_t s, const u16* A, const u16* Wq,
                              const u16* Wk, const u16* Wv, const float* bq,
                              const float* bk, const float* bv, u16* out,
                              int M, int N, int K) {
    dim3 grid(N / 128, M / 128, 3);
    gemm_bt<true, true, true><<<grid, 256, 0, s>>>(A, K, Wq, Wk, Wv, bq, bk, bv,
                                                   out, (size_t)M * N, M, N, K);
}

extern "C" void kernel_launch(void* const* d_in, const int* in_sizes, int n_in,
                              void* d_out, int out_size, void* d_ws, size_t ws_size,
                              hipStream_t stream) {
    const float* fc      = (const float*)d_in[0];
    const float* nsa_Wq  = (const float*)d_in[1];
    const float* nsa_Wk  = (const float*)d_in[2];
    const float* nsa_Wv  = (const float*)d_in[3];
    const float* nsa_bq  = (const float*)d_in[4];
    const float* nsa_bk  = (const float*)d_in[5];
    const float* nsa_bv  = (const float*)d_in[6];
    const float* nsa_Wih = (const float*)d_in[7];
    const float* nsa_Whh = (const float*)d_in[8];
    const float* nsa_bih = (const float*)d_in[9];
    const float* nsa_bhh = (const float*)d_in[10];
    const float* sa_Wq   = (const float*)d_in[11];
    const float* sa_Wk   = (const float*)d_in[12];
    const float* sa_Wv   = (const float*)d_in[13];
    const float* sa_bq   = (const float*)d_in[14];
    const float* sa_bk   = (const float*)d_in[15];
    const float* sa_bv   = (const float*)d_in[16];
    const float* sa_Wih  = (const float*)d_in[17];
    const float* sa_Whh  = (const float*)d_in[18];
    const float* sa_bih  = (const float*)d_in[19];
    const float* sa_bhh  = (const float*)d_in[20];
    const float* ln_g    = (const float*)d_in[21];
    const float* ln_b    = (const float*)d_in[22];

    float* outF   = (float*)d_out;
    float* out_sa = outF;            // (64,2048)
    float* out_ln = outF + 131072;   // (64,16,2048)

    char* W = (char*)d_ws;
    // --- workspace layout (peak 240 MiB) ---
    u16* W_q   = (u16*)(W + 0);          // 8,388,608 each; nsa->sa; h1/c1/h1bf alias during LSTM
    u16* W_k   = (u16*)(W + 8388608);
    u16* W_v   = (u16*)(W + 16777216);
    u16* W_ih  = (u16*)(W + 25165824);   // 33,554,432 (nsa_Wih -> sa_Wih)
    u16* W_hh1 = (u16*)(W + 58720256);   // 33,554,432 (nsa_Whh)
    u16* W_hh2 = (u16*)(W + 92274688);   // 33,554,432 (sa_Whh)
    u16*   Xbf  = (u16*)(W + 125829120); // 5,242,880 (fc bf16; lnbf alias)
    u16*   q0   = (u16*)(W + 131072000); // q0/k0/v0 15,728,640; hW alias; q2/k2/v2; partials
    u16*   att1 = (u16*)(W + 146800640); // 20,971,520 (att1/att2)
    u16*   xg   = (u16*)(W + 167772160); // 83,886,080 bf16 (5120x8192; xg2 subset)
    // aliases:
    float* h1   = (float*)(W + 0);          // 1024x2048 f32 (during/after nsa LSTM, until LN)
    float* c1   = (float*)(W + 8388608);    // 1024x2048 f32
    u16*   h1bf = (u16*)(W + 16777216);     // 1024x2048 bf16
    float* hW1  = (float*)(W + 131072000);  // 1024x8192 f32 (during nsa LSTM; q0..att1-head dead)
    u16*   lnbf = Xbf;                      // 1024x2048 bf16
    u16*   q2   = q0;                       // 3 x 1024x2048 bf16, tight-packed
    u16*   att2 = att1;
    float* hW2  = (float*)(W + 131072000);  // 4 partials 64x8192 f32 = 8,388,608
    float* h2   = (float*)(W + 139460608);  // 64x2048 f32
    float* c2   = (float*)(W + 139984896);
    u16*   h2bf = (u16*)(W + 140509184);

    // 0) convert fc + nsa weights + sa_Whh to bf16 (one fused kernel)
    {
        CvtArgs a{};
        a.src[0] = fc;      a.dst[0] = Xbf;   a.n4[0] = 655360;
        a.src[1] = nsa_Wq;  a.dst[1] = W_q;   a.n4[1] = 1048576;
        a.src[2] = nsa_Wk;  a.dst[2] = W_k;   a.n4[2] = 1048576;
        a.src[3] = nsa_Wv;  a.dst[3] = W_v;   a.n4[3] = 1048576;
        a.src[4] = nsa_Wih; a.dst[4] = W_ih;  a.n4[4] = 4194304;
        a.src[5] = nsa_Whh; a.dst[5] = W_hh1; a.n4[5] = 4194304;
        a.src[6] = sa_Whh;  a.dst[6] = W_hh2; a.n4[6] = 4194304;
        a.nseg = 7;
        cvt_multi<<<2048, 256, 0, stream>>>(a);
    }

    // 1) nsa QKV on the 1280 unique rows (one z=3 dispatch, 480 blocks)
    launch_qkv(stream, Xbf, W_q, W_k, W_v, nsa_bq, nsa_bk, nsa_bv, q0, 1280, 2048, 2048);

    // 2) windowed attention
    attn_win5<<<1024, 256, 0, stream>>>(q0, q0 + 2621440, q0 + 5242880, att1);

    // 3) xg for ALL 5 steps: one M=5120 GEMM (2560 blocks), bf16 out
    launch_gemm1(stream, att1, 2048, W_ih, xg, 5120, 8192, 2048, true);

    // 4) nsa LSTM over 5 steps (rows = 1024 windows)
    lstm_gate<0><<<2048, 256, 0, stream>>>(xg, 40960, nullptr, nsa_bih, nsa_bhh,
                                           c1, h1, h1bf, nullptr, 1024);
    for (int t = 1; t < 5; ++t) {
        launch_gemm1(stream, h1bf, 2048, W_hh1, hW1, 1024, 8192, 2048, false);
        lstm_gate<1><<<2048, 256, 0, stream>>>(xg + (size_t)t * 8192, 40960, hW1,
                                               nsa_bih, nsa_bhh, c1, h1, h1bf,
                                               nullptr, 1024);
    }

    // 5) LayerNorm -> output 1 (fp32) + bf16 copy for stage 2
    layernorm_k<<<1024, 256, 0, stream>>>(h1, ln_g, ln_b, out_ln, lnbf);

    // 5b) convert sa single-use weights into the (now dead) nsa slots
    {
        CvtArgs a{};
        a.src[0] = sa_Wq;  a.dst[0] = W_q;  a.n4[0] = 1048576;
        a.src[1] = sa_Wk;  a.dst[1] = W_k;  a.n4[1] = 1048576;
        a.src[2] = sa_Wv;  a.dst[2] = W_v;  a.n4[2] = 1048576;
        a.src[3] = sa_Wih; a.dst[3] = W_ih; a.n4[3] = 4194304;
        a.nseg = 4;
        cvt_multi<<<2048, 256, 0, stream>>>(a);
    }

    // 6) sa QKV (one z=3 dispatch, 384 blocks)
    launch_qkv(stream, lnbf, W_q, W_k, W_v, sa_bq, sa_bk, sa_bv, q2, 1024, 2048, 2048);

    // 7) seq-16 attention
    attn_seq16<<<1024, 256, 0, stream>>>(q2, q2 + 2097152, q2 + 4194304, att2);

    // 8) xg2 = att2 @ saWih^T (bf16 out)
    launch_gemm1(stream, att2, 2048, W_ih, xg, 1024, 8192, 2048, true);

    // 9) sa LSTM over 16 steps (rows = 64); recurrent GEMM = skinny split-K=4
    lstm_gate<0><<<128, 256, 0, stream>>>(xg, 131072, nullptr, sa_bih, sa_bhh,
                                          c2, h2, h2bf, nullptr, 64);
    for (int t = 1; t < 16; ++t) {
        gemm_skinny64<<<dim3(64, 4), 256, 0, stream>>>(h2bf, W_hh2, hW2, 8192, 2048);
        lstm_gate<4><<<128, 256, 0, stream>>>(xg + (size_t)t * 8192, 131072, hW2,
                                              sa_bih, sa_bhh, c2, h2, h2bf,
                                              (t == 15) ? out_sa : nullptr, 64);
    }
}

// Round 4
// 1029.688 us; speedup vs baseline: 1.8942x; 1.0463x over previous
//
#include <hip/hip_runtime.h>
#include <hip/hip_bf16.h>

typedef unsigned int  u32;
typedef unsigned short u16;

typedef __bf16 bf16x8 __attribute__((ext_vector_type(8)));
typedef float  f32x4  __attribute__((ext_vector_type(4)));

#define D2048 2048
#define SCALE 0.022097086912079612f

__device__ __forceinline__ u32 f2bfbits(float f) {
    u32 u = __float_as_uint(f);
    return (u + 0x7FFFu + ((u >> 16) & 1u)) >> 16;   // RNE
}
__device__ __forceinline__ u32 pack2(float a, float b) {
    return f2bfbits(a) | (f2bfbits(b) << 16);
}
__device__ __forceinline__ float bf2f(u32 h) {
    return __uint_as_float(h << 16);
}
__device__ __forceinline__ void unpack8(uint4 v, float* f) {
    f[0] = bf2f(v.x & 0xFFFFu); f[1] = bf2f(v.x >> 16);
    f[2] = bf2f(v.y & 0xFFFFu); f[3] = bf2f(v.y >> 16);
    f[4] = bf2f(v.z & 0xFFFFu); f[5] = bf2f(v.z >> 16);
    f[6] = bf2f(v.w & 0xFFFFu); f[7] = bf2f(v.w >> 16);
}
__device__ __forceinline__ float sigmf(float x) { return 1.f / (1.f + __expf(-x)); }
__device__ __forceinline__ float tanhf_(float x) {
    x = fminf(15.f, fmaxf(-15.f, x));
    float e = __expf(2.f * x);
    return (e - 1.f) / (e + 1.f);
}

// async global->LDS, 16B per lane. LDS dest: wave-uniform base + lane*16B.
__device__ __forceinline__ void gload_lds16(const u16* g, u16* l) {
    __builtin_amdgcn_global_load_lds(
        (const __attribute__((address_space(1))) unsigned int*)g,
        (__attribute__((address_space(3))) unsigned int*)l,
        16, 0, 0);
}

// ---------------------------------------------------------------------------
// Multi-segment fp32 -> bf16 conversion (grid-stride per segment)
// ---------------------------------------------------------------------------
struct CvtArgs {
    const float* src[8];
    u16*         dst[8];
    int          n4[8];
    int          nseg;
};
__global__ __launch_bounds__(256) void cvt_multi(CvtArgs a) {
    int stride = gridDim.x * 256;
    for (int s = 0; s < a.nseg; ++s) {
        const float4* S = reinterpret_cast<const float4*>(a.src[s]);
        uint2*        D = reinterpret_cast<uint2*>(a.dst[s]);
        int n4 = a.n4[s];
        for (int i = blockIdx.x * 256 + threadIdx.x; i < n4; i += stride) {
            float4 v = S[i];
            uint2 p;
            p.x = pack2(v.x, v.y);
            p.y = pack2(v.z, v.w);
            D[i] = p;
        }
    }
}

// ---------------------------------------------------------------------------
// 256x256 8-phase GEMM: C[M][N] = A[M][K](bf16, stride lda) * B[N][K](bf16)^T
// BK=64, 512 threads (8 waves, 2M x 4N), per-wave 128x64 output (acc[8][4]).
// LDS 128 KiB: A/B tiles 256x64 bf16, double-buffered. XOR chunk swizzle
// (chunk ^= row&7) applied on the GLOBAL source (global_load_lds writes
// linearly) and on the ds_read address -> conflict-free ds_read_b128.
// Per K-tile: 4 phases {ds_read frags | 2 stage loads | barrier | setprio(1)
// 16 MFMA setprio(0) | barrier}; counted vmcnt(2) at iteration top.
// SPLITK=2: blockIdx.z picks K-half; f32 partial to C0 (z=0) / C1 (z=1).
// Requires M%256==0, N%256==0, (K/SPLITK)%64==0.
// ---------------------------------------------------------------------------
template <int SPLITK, bool OUT_BF16>
__global__ __launch_bounds__(512, 2) void gemm256(const u16* __restrict__ A, int lda,
                                                  const u16* __restrict__ B,
                                                  void* __restrict__ C0,
                                                  void* __restrict__ C1,
                                                  int M, int N, int K) {
    __shared__ u16 Ab[2][16384];
    __shared__ u16 Bb[2][16384];

    const int tid  = threadIdx.x;
    const int lane = tid & 63;
    const int wid  = tid >> 6;       // 0..7
    const int wm   = wid >> 2;       // 0..1
    const int wn   = wid & 3;        // 0..3
    const int l15  = lane & 15, l4 = lane >> 4;
    const int rowBase = blockIdx.y * 256;
    const int colBase = blockIdx.x * 256;
    const int kseg = K / SPLITK;
    const int kBeg = (SPLITK > 1) ? (int)blockIdx.z * kseg : 0;

    // staging source (pre-swizzled: LDS chunk c' holds global chunk c'^(row&7))
    const int srow8 = lane >> 3;                   // row-within-8 (== row&7)
    const int scw   = ((lane & 7) ^ srow8) * 8;    // swizzled 16B chunk -> elems
    const u16* gA = A + (size_t)(rowBase + wid * 8 + srow8) * lda + kBeg + scw;
    const u16* gB = B + (size_t)(colBase + wid * 8 + srow8) * (size_t)K + kBeg + scw;
    const int ldsW = wid * 512;                    // wave base within 64-row chunk

#define STAGE_A(buf, koff, q) \
    gload_lds16(gA + (size_t)((q) * 64) * lda + (koff), &Ab[buf][(q) * 4096 + ldsW])
#define STAGE_B(buf, koff, q) \
    gload_lds16(gB + (size_t)((q) * 64) * (size_t)K + (koff), &Bb[buf][(q) * 4096 + ldsW])

    f32x4 acc[8][4];
#pragma unroll
    for (int m = 0; m < 8; m++)
#pragma unroll
        for (int n = 0; n < 4; n++) acc[m][n] = f32x4{0.f, 0.f, 0.f, 0.f};

    const int nt = kseg >> 6;

    // prologue: stage tile 0 fully into buffer 0 (8 loads)
#pragma unroll
    for (int q = 0; q < 4; ++q) { STAGE_A(0, 0, q); STAGE_B(0, 0, q); }

    const int swzA = (l15 & 7);  // row&7 for all frag rows (row ≡ l15 mod 16)

    for (int t = 0; t < nt; ++t) {
        const int cur = t & 1;
        const int nxt = cur ^ 1;
        const int kN  = (t + 1) << 6;
        const bool more = (t + 1 < nt);

        if (more) {
            STAGE_A(nxt, kN, 0);
            STAGE_A(nxt, kN, 1);
            asm volatile("s_waitcnt vmcnt(2)" ::: "memory");
        } else {
            asm volatile("s_waitcnt vmcnt(0)" ::: "memory");
        }
        __builtin_amdgcn_s_barrier();

        // B fragments for the whole K-tile (8 x ds_read_b128), kept in regs
        bf16x8 bfrag[4][2];
#pragma unroll
        for (int n = 0; n < 4; ++n)
#pragma unroll
            for (int kk = 0; kk < 2; ++kk)
                bfrag[n][kk] = *reinterpret_cast<const bf16x8*>(
                    &Bb[cur][(wn * 64 + n * 16 + l15) * 64 +
                             (((kk * 4 + l4) ^ swzA) * 8)]);

#pragma unroll
        for (int p = 0; p < 4; ++p) {
            bf16x8 afr[2][2];
#pragma unroll
            for (int mi = 0; mi < 2; ++mi)
#pragma unroll
                for (int kk = 0; kk < 2; ++kk)
                    afr[mi][kk] = *reinterpret_cast<const bf16x8*>(
                        &Ab[cur][(wm * 128 + (p * 2 + mi) * 16 + l15) * 64 +
                                 (((kk * 4 + l4) ^ swzA) * 8)]);
            if (more) {
                if (p == 0)      { STAGE_A(nxt, kN, 2); STAGE_A(nxt, kN, 3); }
                else if (p == 1) { STAGE_B(nxt, kN, 0); STAGE_B(nxt, kN, 1); }
                else if (p == 2) { STAGE_B(nxt, kN, 2); STAGE_B(nxt, kN, 3); }
            }
            __builtin_amdgcn_s_barrier();
            __builtin_amdgcn_sched_barrier(0);
            __builtin_amdgcn_s_setprio(1);
#pragma unroll
            for (int kk = 0; kk < 2; ++kk)
#pragma unroll
                for (int mi = 0; mi < 2; ++mi)
#pragma unroll
                    for (int n = 0; n < 4; ++n)
                        acc[p * 2 + mi][n] = __builtin_amdgcn_mfma_f32_16x16x32_bf16(
                            afr[mi][kk], bfrag[n][kk], acc[p * 2 + mi][n], 0, 0, 0);
            __builtin_amdgcn_s_setprio(0);
            __builtin_amdgcn_sched_barrier(0);
            __builtin_amdgcn_s_barrier();
        }
    }
#undef STAGE_A
#undef STAGE_B

    // C/D layout: col=lane&15, row=(lane>>4)*4+reg
    float* fdst = (SPLITK > 1 && blockIdx.z) ? (float*)C1 : (float*)C0;
#pragma unroll
    for (int m = 0; m < 8; ++m) {
        int row0 = rowBase + wm * 128 + m * 16 + l4 * 4;
#pragma unroll
        for (int n = 0; n < 4; ++n) {
            int col = colBase + wn * 64 + n * 16 + l15;
#pragma unroll
            for (int rr = 0; rr < 4; ++rr) {
                if (OUT_BF16)
                    ((u16*)C0)[(size_t)(row0 + rr) * N + col] = (u16)f2bfbits(acc[m][n][rr]);
                else
                    fdst[(size_t)(row0 + rr) * N + col] = acc[m][n][rr];
            }
        }
    }
}

// ---------------------------------------------------------------------------
// GEMM: C[M][N] = A[M][K](bf16, row stride lda) * B[N][K](bf16)^T (+bias)
// 128x128 tile, BK=64, 4 waves, global_load_lds width-16, double-buffered
// 2-phase pipeline. Used for the N=2048 QKV projections (grid z=3).
// ---------------------------------------------------------------------------
template <bool QKV3, bool HAS_BIAS, bool OUT_BF16>
__global__ __launch_bounds__(256) void gemm_bt(const u16* __restrict__ A, int lda,
                                               const u16* __restrict__ B0,
                                               const u16* __restrict__ B1,
                                               const u16* __restrict__ B2,
                                               const float* __restrict__ bias0,
                                               const float* __restrict__ bias1,
                                               const float* __restrict__ bias2,
                                               void* __restrict__ Cout,
                                               size_t zCstride,
                                               int M, int N, int K) {
    __shared__ u16 Abuf[2][128 * 64];
    __shared__ u16 Bbuf[2][128 * 64];

    const int tid  = threadIdx.x;
    const int lane = tid & 63;
    const int wave = tid >> 6;
    const int wr   = (wave >> 1) * 64;
    const int wc   = (wave & 1) * 64;
    const int rowBase = blockIdx.y * 128;
    const int colBase = blockIdx.x * 128;
    const int l15 = lane & 15, l4 = lane >> 4;
    const int srow = lane >> 3;        // 0..7
    const int scol = (lane & 7) * 8;   // bf16 col within BK

    const u16* B = B0;
    const float* bias = bias0;
    void* C = Cout;
    if (QKV3) {
        int z = blockIdx.z;
        B    = (z == 0) ? B0 : ((z == 1) ? B1 : B2);
        bias = (z == 0) ? bias0 : ((z == 1) ? bias1 : bias2);
        C    = OUT_BF16 ? (void*)((u16*)Cout + (size_t)z * zCstride)
                        : (void*)((float*)Cout + (size_t)z * zCstride);
    }

    const u16* ga = A + (size_t)(rowBase + wave * 32 + srow) * lda + scol;
    const u16* gb = B + (size_t)(colBase + wave * 32 + srow) * K + scol;
    const int ldsOff = (wave * 32) * 64;

    f32x4 acc[4][4];
#pragma unroll
    for (int i = 0; i < 4; i++)
#pragma unroll
        for (int j = 0; j < 4; j++) acc[i][j] = f32x4{0.f, 0.f, 0.f, 0.f};

    const int nt = K >> 6;

#pragma unroll
    for (int i = 0; i < 4; ++i) {
        gload_lds16(ga + (size_t)(i * 8) * lda, &Abuf[0][ldsOff + i * 8 * 64]);
        gload_lds16(gb + (size_t)(i * 8) * K,   &Bbuf[0][ldsOff + i * 8 * 64]);
    }

    for (int t = 0; t < nt; ++t) {
        const int cur = t & 1;
        if (t + 1 < nt) {
            const int k1 = (t + 1) << 6;
#pragma unroll
            for (int i = 0; i < 4; ++i) {
                gload_lds16(ga + (size_t)(i * 8) * lda + k1,
                            &Abuf[cur ^ 1][ldsOff + i * 8 * 64]);
                gload_lds16(gb + (size_t)(i * 8) * K + k1,
                            &Bbuf[cur ^ 1][ldsOff + i * 8 * 64]);
            }
            asm volatile("s_waitcnt vmcnt(8)" ::: "memory");
        } else {
            asm volatile("s_waitcnt vmcnt(0)" ::: "memory");
        }
        __builtin_amdgcn_s_barrier();
        __builtin_amdgcn_sched_barrier(0);
#pragma unroll
        for (int kk = 0; kk < 2; ++kk) {
            bf16x8 af[4], bfr[4];
#pragma unroll
            for (int i = 0; i < 4; i++) {
                af[i]  = *reinterpret_cast<const bf16x8*>(
                    &Abuf[cur][(wr + i * 16 + l15) * 64 + kk * 32 + l4 * 8]);
                bfr[i] = *reinterpret_cast<const bf16x8*>(
                    &Bbuf[cur][(wc + i * 16 + l15) * 64 + kk * 32 + l4 * 8]);
            }
#pragma unroll
            for (int i = 0; i < 4; i++)
#pragma unroll
                for (int j = 0; j < 4; j++)
                    acc[i][j] = __builtin_amdgcn_mfma_f32_16x16x32_bf16(af[i], bfr[j],
                                                                        acc[i][j], 0, 0, 0);
        }
        __builtin_amdgcn_sched_barrier(0);
        __builtin_amdgcn_s_barrier();
    }

#pragma unroll
    for (int i = 0; i < 4; i++) {
        int row0 = rowBase + wr + i * 16 + l4 * 4;
#pragma unroll
        for (int j = 0; j < 4; j++) {
            int col = colBase + wc + j * 16 + l15;
            float bv = HAS_BIAS ? bias[col] : 0.f;
#pragma unroll
            for (int rr = 0; rr < 4; rr++) {
                float val = acc[i][j][rr] + bv;
                if (OUT_BF16)
                    ((u16*)C)[(size_t)(row0 + rr) * N + col] = (u16)f2bfbits(val);
                else
                    ((float*)C)[(size_t)(row0 + rr) * N + col] = val;
            }
        }
    }
}

// ---------------------------------------------------------------------------
// Skinny GEMM for the sa recurrence: C_part[kp] = A[64][Kseg] * B[N][Kseg]^T
// Tile 64x128, 4 waves, split-K=8 over gridDim.y, double-buffered pipeline.
// ---------------------------------------------------------------------------
__global__ __launch_bounds__(256) void gemm_skinny64(const u16* __restrict__ A,
                                                     const u16* __restrict__ B,
                                                     float* __restrict__ part,
                                                     int N, int K) {
    __shared__ u16 Abuf[2][64 * 64];
    __shared__ u16 Bbuf[2][128 * 64];
    const int tid = threadIdx.x, lane = tid & 63, wave = tid >> 6;
    const int colBase = blockIdx.x * 128;
    const int kp = blockIdx.y;
    const int kseg = K >> 3;
    const int kBeg = kp * kseg;
    const int l15 = lane & 15, l4 = lane >> 4;
    const int srow = lane >> 3, scol = (lane & 7) * 8;

    const u16* ga = A + (size_t)(wave * 16 + srow) * K + scol + kBeg;
    const u16* gb = B + (size_t)(colBase + wave * 32 + srow) * K + scol + kBeg;
    const int laOff = (wave * 16) * 64;
    const int lbOff = (wave * 32) * 64;

    f32x4 acc[4][2];
#pragma unroll
    for (int i = 0; i < 4; i++)
#pragma unroll
        for (int j = 0; j < 2; j++) acc[i][j] = f32x4{0.f, 0.f, 0.f, 0.f};

    const int nt = kseg >> 6;

#pragma unroll
    for (int i = 0; i < 2; ++i)
        gload_lds16(ga + (size_t)(i * 8) * K, &Abuf[0][laOff + i * 8 * 64]);
#pragma unroll
    for (int i = 0; i < 4; ++i)
        gload_lds16(gb + (size_t)(i * 8) * K, &Bbuf[0][lbOff + i * 8 * 64]);

    for (int t = 0; t < nt; ++t) {
        const int cur = t & 1;
        if (t + 1 < nt) {
            const int k1 = (t + 1) << 6;
#pragma unroll
            for (int i = 0; i < 2; ++i)
                gload_lds16(ga + (size_t)(i * 8) * K + k1, &Abuf[cur ^ 1][laOff + i * 8 * 64]);
#pragma unroll
            for (int i = 0; i < 4; ++i)
                gload_lds16(gb + (size_t)(i * 8) * K + k1, &Bbuf[cur ^ 1][lbOff + i * 8 * 64]);
            asm volatile("s_waitcnt vmcnt(6)" ::: "memory");
        } else {
            asm volatile("s_waitcnt vmcnt(0)" ::: "memory");
        }
        __builtin_amdgcn_s_barrier();
        __builtin_amdgcn_sched_barrier(0);
#pragma unroll
        for (int kk = 0; kk < 2; ++kk) {
            bf16x8 af[4], bfr[2];
#pragma unroll
            for (int i = 0; i < 4; i++)
                af[i] = *reinterpret_cast<const bf16x8*>(
                    &Abuf[cur][(i * 16 + l15) * 64 + kk * 32 + l4 * 8]);
#pragma unroll
            for (int j = 0; j < 2; j++)
                bfr[j] = *reinterpret_cast<const bf16x8*>(
                    &Bbuf[cur][(wave * 32 + j * 16 + l15) * 64 + kk * 32 + l4 * 8]);
#pragma unroll
            for (int i = 0; i < 4; i++)
#pragma unroll
                for (int j = 0; j < 2; j++)
                    acc[i][j] = __builtin_amdgcn_mfma_f32_16x16x32_bf16(af[i], bfr[j],
                                                                        acc[i][j], 0, 0, 0);
        }
        __builtin_amdgcn_sched_barrier(0);
        __builtin_amdgcn_s_barrier();
    }

    float* cp = part + (size_t)kp * 64 * N;
#pragma unroll
    for (int i = 0; i < 4; i++) {
        int row0 = i * 16 + l4 * 4;
#pragma unroll
        for (int j = 0; j < 2; j++) {
            int col = colBase + wave * 32 + j * 16 + l15;
#pragma unroll
            for (int rr = 0; rr < 4; rr++)
                cp[(size_t)(row0 + rr) * N + col] = acc[i][j][rr];
        }
    }
}

// ---------------------------------------------------------------------------
// Attention over 5-windows. One block per window n = b*16+t.
// ---------------------------------------------------------------------------
__global__ __launch_bounds__(256) void attn_win5(const u16* __restrict__ q0,
                                                 const u16* __restrict__ k0,
                                                 const u16* __restrict__ v0,
                                                 u16* __restrict__ att) {
    int n = blockIdx.x;  // 0..1023
    int b = n >> 4, t = n & 15;
    int tid = threadIdx.x, lane = tid & 63, wave = tid >> 6;
    int d0 = tid * 8;
    size_t base = (size_t)(b * 20 + t) * D2048;

    float qv[5][8];
#pragma unroll
    for (int i = 0; i < 5; i++) {
        uint4 v = *reinterpret_cast<const uint4*>(q0 + base + (size_t)i * D2048 + d0);
        unpack8(v, qv[i]);
    }
    float part[25];
#pragma unroll
    for (int p = 0; p < 25; p++) part[p] = 0.f;
#pragma unroll
    for (int m = 0; m < 5; m++) {
        float kv[8];
        uint4 v = *reinterpret_cast<const uint4*>(k0 + base + (size_t)m * D2048 + d0);
        unpack8(v, kv);
#pragma unroll
        for (int l = 0; l < 5; l++)
#pragma unroll
            for (int j = 0; j < 8; j++) part[l * 5 + m] += qv[l][j] * kv[j];
    }
#pragma unroll
    for (int p = 0; p < 25; p++) {
        float s = part[p];
#pragma unroll
        for (int msk = 32; msk; msk >>= 1) s += __shfl_xor(s, msk, 64);
        part[p] = s;
    }
    __shared__ float wred[4][25];
    __shared__ float wmat[25];
    if (lane == 0) {
#pragma unroll
        for (int p = 0; p < 25; p++) wred[wave][p] = part[p];
    }
    __syncthreads();
    if (tid < 5) {
        int l = tid;
        float dv[5], mx = -1e30f;
#pragma unroll
        for (int m = 0; m < 5; m++) {
            dv[m] = (wred[0][l * 5 + m] + wred[1][l * 5 + m] + wred[2][l * 5 + m] +
                     wred[3][l * 5 + m]) * SCALE;
            mx = fmaxf(mx, dv[m]);
        }
        float ssum = 0.f;
#pragma unroll
        for (int m = 0; m < 5; m++) { dv[m] = __expf(dv[m] - mx); ssum += dv[m]; }
        float inv = 1.f / ssum;
#pragma unroll
        for (int m = 0; m < 5; m++) wmat[l * 5 + m] = dv[m] * inv;
    }
    __syncthreads();

    float oacc[5][8];
#pragma unroll
    for (int l = 0; l < 5; l++)
#pragma unroll
        for (int j = 0; j < 8; j++) oacc[l][j] = 0.f;
#pragma unroll
    for (int m = 0; m < 5; m++) {
        float vv[8];
        uint4 v = *reinterpret_cast<const uint4*>(v0 + base + (size_t)m * D2048 + d0);
        unpack8(v, vv);
#pragma unroll
        for (int l = 0; l < 5; l++) {
            float w = wmat[l * 5 + m];
#pragma unroll
            for (int j = 0; j < 8; j++) oacc[l][j] += w * vv[j];
        }
    }
#pragma unroll
    for (int l = 0; l < 5; l++) {
        uint4 p;
        p.x = pack2(oacc[l][0], oacc[l][1]);
        p.y = pack2(oacc[l][2], oacc[l][3]);
        p.z = pack2(oacc[l][4], oacc[l][5]);
        p.w = pack2(oacc[l][6], oacc[l][7]);
        *reinterpret_cast<uint4*>(att + (size_t)(n * 5 + l) * D2048 + d0) = p;
    }
}

// ---------------------------------------------------------------------------
// Attention over seq-16. One block per output row r = b*16 + l.
// ---------------------------------------------------------------------------
__global__ __launch_bounds__(256) void attn_seq16(const u16* __restrict__ q2,
                                                  const u16* __restrict__ k2,
                                                  const u16* __restrict__ v2,
                                                  u16* __restrict__ att2) {
    int r = blockIdx.x;  // 0..1023
    int b = r >> 4;
    int tid = threadIdx.x, lane = tid & 63, wave = tid >> 6;
    int d0 = tid * 8;
    size_t kbase = (size_t)b * 16 * D2048;

    float qv[8];
    {
        uint4 v = *reinterpret_cast<const uint4*>(q2 + (size_t)r * D2048 + d0);
        unpack8(v, qv);
    }
    float part[16];
#pragma unroll
    for (int m = 0; m < 16; m++) part[m] = 0.f;
#pragma unroll
    for (int m = 0; m < 16; m++) {
        float kv[8];
        uint4 v = *reinterpret_cast<const uint4*>(k2 + kbase + (size_t)m * D2048 + d0);
        unpack8(v, kv);
#pragma unroll
        for (int j = 0; j < 8; j++) part[m] += qv[j] * kv[j];
    }
#pragma unroll
    for (int m = 0; m < 16; m++) {
        float s = part[m];
#pragma unroll
        for (int msk = 32; msk; msk >>= 1) s += __shfl_xor(s, msk, 64);
        part[m] = s;
    }
    __shared__ float wred[4][16];
    __shared__ float wmat[16];
    if (lane == 0) {
#pragma unroll
        for (int m = 0; m < 16; m++) wred[wave][m] = part[m];
    }
    __syncthreads();
    if (tid == 0) {
        float dv[16], mx = -1e30f;
#pragma unroll
        for (int m = 0; m < 16; m++) {
            dv[m] = (wred[0][m] + wred[1][m] + wred[2][m] + wred[3][m]) * SCALE;
            mx = fmaxf(mx, dv[m]);
        }
        float ssum = 0.f;
#pragma unroll
        for (int m = 0; m < 16; m++) { dv[m] = __expf(dv[m] - mx); ssum += dv[m]; }
        float inv = 1.f / ssum;
#pragma unroll
        for (int m = 0; m < 16; m++) wmat[m] = dv[m] * inv;
    }
    __syncthreads();

    float oacc[8];
#pragma unroll
    for (int j = 0; j < 8; j++) oacc[j] = 0.f;
#pragma unroll
    for (int m = 0; m < 16; m++) {
        float vv[8];
        uint4 v = *reinterpret_cast<const uint4*>(v2 + kbase + (size_t)m * D2048 + d0);
        unpack8(v, vv);
        float w = wmat[m];
#pragma unroll
        for (int j = 0; j < 8; j++) oacc[j] += w * vv[j];
    }
    uint4 p;
    p.x = pack2(oacc[0], oacc[1]);
    p.y = pack2(oacc[2], oacc[3]);
    p.z = pack2(oacc[4], oacc[5]);
    p.w = pack2(oacc[6], oacc[7]);
    *reinterpret_cast<uint4*>(att2 + (size_t)r * D2048 + d0) = p;
}

// ---------------------------------------------------------------------------
// LSTM gate update. xg bf16 (row stride xg_stride elems). NPARTS==0: first
// step (c=0, no hW). NPARTS==2: two separately-placed f32 partials hWa,hWb.
// NPARTS==8: 8 f32 partials at hWa + p*524288 (64-row split-K buffers).
// ---------------------------------------------------------------------------
template <int NPARTS>
__global__ __launch_bounds__(256) void lstm_gate(const u16* __restrict__ xg,
                                                 int xg_stride,
                                                 const float* __restrict__ hWa,
                                                 const float* __restrict__ hWb,
                                                 const float* __restrict__ bih,
                                                 const float* __restrict__ bhh,
                                                 float* __restrict__ c,
                                                 float* __restrict__ h,
                                                 u16* __restrict__ hbf,
                                                 float* __restrict__ hout,
                                                 int rows) {
    int idx = blockIdx.x * 256 + threadIdx.x;
    int total = rows * 512;
    if (idx >= total) return;
    int n  = idx >> 9;
    int j4 = (idx & 511) * 4;

    const u16* xr = xg + (size_t)n * xg_stride + j4;
    float4 gi, gf, gg, go;
    {
        uint2 ri = *reinterpret_cast<const uint2*>(xr);
        uint2 rf = *reinterpret_cast<const uint2*>(xr + 2048);
        uint2 rg = *reinterpret_cast<const uint2*>(xr + 4096);
        uint2 ro = *reinterpret_cast<const uint2*>(xr + 6144);
        gi = {bf2f(ri.x & 0xFFFFu), bf2f(ri.x >> 16), bf2f(ri.y & 0xFFFFu), bf2f(ri.y >> 16)};
        gf = {bf2f(rf.x & 0xFFFFu), bf2f(rf.x >> 16), bf2f(rf.y & 0xFFFFu), bf2f(rf.y >> 16)};
        gg = {bf2f(rg.x & 0xFFFFu), bf2f(rg.x >> 16), bf2f(rg.y & 0xFFFFu), bf2f(rg.y >> 16)};
        go = {bf2f(ro.x & 0xFFFFu), bf2f(ro.x >> 16), bf2f(ro.y & 0xFFFFu), bf2f(ro.y >> 16)};
    }

    float4 bi1 = *reinterpret_cast<const float4*>(bih + j4);
    float4 bf1 = *reinterpret_cast<const float4*>(bih + 2048 + j4);
    float4 bg1 = *reinterpret_cast<const float4*>(bih + 4096 + j4);
    float4 bo1 = *reinterpret_cast<const float4*>(bih + 6144 + j4);
    float4 bi2 = *reinterpret_cast<const float4*>(bhh + j4);
    float4 bf2_ = *reinterpret_cast<const float4*>(bhh + 2048 + j4);
    float4 bg2 = *reinterpret_cast<const float4*>(bhh + 4096 + j4);
    float4 bo2 = *reinterpret_cast<const float4*>(bhh + 6144 + j4);

    gi.x += bi1.x + bi2.x; gi.y += bi1.y + bi2.y; gi.z += bi1.z + bi2.z; gi.w += bi1.w + bi2.w;
    gf.x += bf1.x + bf2_.x; gf.y += bf1.y + bf2_.y; gf.z += bf1.z + bf2_.z; gf.w += bf1.w + bf2_.w;
    gg.x += bg1.x + bg2.x; gg.y += bg1.y + bg2.y; gg.z += bg1.z + bg2.z; gg.w += bg1.w + bg2.w;
    go.x += bo1.x + bo2.x; go.y += bo1.y + bo2.y; go.z += bo1.z + bo2.z; go.w += bo1.w + bo2.w;

#pragma unroll
    for (int p = 0; p < NPARTS; ++p) {
        const float* hr = (NPARTS == 2)
            ? ((p == 0 ? hWa : hWb) + (size_t)n * 8192)
            : (hWa + (size_t)p * 524288 + (size_t)n * 8192);
        float4 hi = *reinterpret_cast<const float4*>(hr + j4);
        float4 hf = *reinterpret_cast<const float4*>(hr + 2048 + j4);
        float4 hg = *reinterpret_cast<const float4*>(hr + 4096 + j4);
        float4 ho = *reinterpret_cast<const float4*>(hr + 6144 + j4);
        gi.x += hi.x; gi.y += hi.y; gi.z += hi.z; gi.w += hi.w;
        gf.x += hf.x; gf.y += hf.y; gf.z += hf.z; gf.w += hf.w;
        gg.x += hg.x; gg.y += hg.y; gg.z += hg.z; gg.w += hg.w;
        go.x += ho.x; go.y += ho.y; go.z += ho.z; go.w += ho.w;
    }
    float4 cc;
    if (NPARTS == 0) { cc.x = cc.y = cc.z = cc.w = 0.f; }
    else             cc = *reinterpret_cast<const float4*>(c + (size_t)n * 2048 + j4);

    float cx = sigmf(gf.x) * cc.x + sigmf(gi.x) * tanhf_(gg.x);
    float cy = sigmf(gf.y) * cc.y + sigmf(gi.y) * tanhf_(gg.y);
    float cz = sigmf(gf.z) * cc.z + sigmf(gi.z) * tanhf_(gg.z);
    float cw = sigmf(gf.w) * cc.w + sigmf(gi.w) * tanhf_(gg.w);
    float hx = sigmf(go.x) * tanhf_(cx);
    float hy = sigmf(go.y) * tanhf_(cy);
    float hz = sigmf(go.z) * tanhf_(cz);
    float hw_ = sigmf(go.w) * tanhf_(cw);

    float4 co = {cx, cy, cz, cw};
    float4 ho_ = {hx, hy, hz, hw_};
    *reinterpret_cast<float4*>(c + (size_t)n * 2048 + j4) = co;
    *reinterpret_cast<float4*>(h + (size_t)n * 2048 + j4) = ho_;
    uint2 hp;
    hp.x = pack2(hx, hy);
    hp.y = pack2(hz, hw_);
    *reinterpret_cast<uint2*>(hbf + (size_t)n * 2048 + j4) = hp;
    if (hout) *reinterpret_cast<float4*>(hout + (size_t)n * 2048 + j4) = ho_;
}

// ---------------------------------------------------------------------------
// LayerNorm over last dim (2048). One block per row. Writes fp32 + bf16 copy.
// ---------------------------------------------------------------------------
__global__ __launch_bounds__(256) void layernorm_k(const float* __restrict__ x,
                                                   const float* __restrict__ g,
                                                   const float* __restrict__ b,
                                                   float* __restrict__ y,
                                                   u16* __restrict__ ybf) {
    int row = blockIdx.x;
    int tid = threadIdx.x, lane = tid & 63, wave = tid >> 6;
    const float* xr = x + (size_t)row * D2048;
    int j = tid * 8;
    float4 v1 = *reinterpret_cast<const float4*>(xr + j);
    float4 v2 = *reinterpret_cast<const float4*>(xr + j + 4);
    float s  = v1.x + v1.y + v1.z + v1.w + v2.x + v2.y + v2.z + v2.w;
    float s2 = v1.x * v1.x + v1.y * v1.y + v1.z * v1.z + v1.w * v1.w +
               v2.x * v2.x + v2.y * v2.y + v2.z * v2.z + v2.w * v2.w;
#pragma unroll
    for (int msk = 32; msk; msk >>= 1) {
        s  += __shfl_xor(s, msk, 64);
        s2 += __shfl_xor(s2, msk, 64);
    }
    __shared__ float red[4][2];
    if (lane == 0) { red[wave][0] = s; red[wave][1] = s2; }
    __syncthreads();
    s  = red[0][0] + red[1][0] + red[2][0] + red[3][0];
    s2 = red[0][1] + red[1][1] + red[2][1] + red[3][1];
    float mu  = s * (1.f / 2048.f);
    float var = s2 * (1.f / 2048.f) - mu * mu;
    float rs  = __frsqrt_rn(var + 1e-5f);

    float4 g1 = *reinterpret_cast<const float4*>(g + j);
    float4 g2 = *reinterpret_cast<const float4*>(g + j + 4);
    float4 b1 = *reinterpret_cast<const float4*>(b + j);
    float4 b2 = *reinterpret_cast<const float4*>(b + j + 4);
    float o[8];
    o[0] = (v1.x - mu) * rs * g1.x + b1.x;
    o[1] = (v1.y - mu) * rs * g1.y + b1.y;
    o[2] = (v1.z - mu) * rs * g1.z + b1.z;
    o[3] = (v1.w - mu) * rs * g1.w + b1.w;
    o[4] = (v2.x - mu) * rs * g2.x + b2.x;
    o[5] = (v2.y - mu) * rs * g2.y + b2.y;
    o[6] = (v2.z - mu) * rs * g2.z + b2.z;
    o[7] = (v2.w - mu) * rs * g2.w + b2.w;
    float4 o1 = {o[0], o[1], o[2], o[3]};
    float4 o2 = {o[4], o[5], o[6], o[7]};
    float* yr = y + (size_t)row * D2048;
    *reinterpret_cast<float4*>(yr + j)     = o1;
    *reinterpret_cast<float4*>(yr + j + 4) = o2;
    uint4 p;
    p.x = pack2(o[0], o[1]);
    p.y = pack2(o[2], o[3]);
    p.z = pack2(o[4], o[5]);
    p.w = pack2(o[6], o[7]);
    *reinterpret_cast<uint4*>(ybf + (size_t)row * D2048 + j) = p;
}

// ---------------------------------------------------------------------------
static inline void launch_qkv(hipStream_t s, const u16* A, const u16* Wq,
                              const u16* Wk, const u16* Wv, const float* bq,
                              const float* bk, const float* bv, u16* out,
                              int M, int N, int K) {
    dim3 grid(N / 128, M / 128, 3);
    gemm_bt<true, true, true><<<grid, 256, 0, s>>>(A, K, Wq, Wk, Wv, bq, bk, bv,
                                                   out, (size_t)M * N, M, N, K);
}

extern "C" void kernel_launch(void* const* d_in, const int* in_sizes, int n_in,
                              void* d_out, int out_size, void* d_ws, size_t ws_size,
                              hipStream_t stream) {
    const float* fc      = (const float*)d_in[0];
    const float* nsa_Wq  = (const float*)d_in[1];
    const float* nsa_Wk  = (const float*)d_in[2];
    const float* nsa_Wv  = (const float*)d_in[3];
    const float* nsa_bq  = (const float*)d_in[4];
    const float* nsa_bk  = (const float*)d_in[5];
    const float* nsa_bv  = (const float*)d_in[6];
    const float* nsa_Wih = (const float*)d_in[7];
    const float* nsa_Whh = (const float*)d_in[8];
    const float* nsa_bih = (const float*)d_in[9];
    const float* nsa_bhh = (const float*)d_in[10];
    const float* sa_Wq   = (const float*)d_in[11];
    const float* sa_Wk   = (const float*)d_in[12];
    const float* sa_Wv   = (const float*)d_in[13];
    const float* sa_bq   = (const float*)d_in[14];
    const float* sa_bk   = (const float*)d_in[15];
    const float* sa_bv   = (const float*)d_in[16];
    const float* sa_Wih  = (const float*)d_in[17];
    const float* sa_Whh  = (const float*)d_in[18];
    const float* sa_bih  = (const float*)d_in[19];
    const float* sa_bhh  = (const float*)d_in[20];
    const float* ln_g    = (const float*)d_in[21];
    const float* ln_b    = (const float*)d_in[22];

    float* outF   = (float*)d_out;
    float* out_sa = outF;            // (64,2048)
    float* out_ln = outF + 131072;   // (64,16,2048)

    char* W = (char*)d_ws;
    u16* W_q   = (u16*)(W + 0);          // nsa->sa QKV weights; h1/c1/h1bf alias
    u16* W_k   = (u16*)(W + 8388608);
    u16* W_v   = (u16*)(W + 16777216);
    u16* W_ih  = (u16*)(W + 25165824);   // nsa_Wih -> (nsa LSTM: partB) -> sa_Wih
    u16* W_hh1 = (u16*)(W + 58720256);   // nsa_Whh
    u16* W_hh2 = (u16*)(W + 92274688);   // sa_Whh
    u16*   Xbf  = (u16*)(W + 125829120); // fc bf16; lnbf alias
    u16*   q0   = (u16*)(W + 131072000); // q0/k0/v0; partA alias; q2/k2/v2; hW2
    u16*   att1 = (u16*)(W + 146800640); // att1/att2
    u16*   xg   = (u16*)(W + 167772160); // 5120x8192 bf16 (xg2 subset)
    // aliases:
    float* h1   = (float*)(W + 0);          // 1024x2048 f32
    float* c1   = (float*)(W + 8388608);    // 1024x2048 f32
    u16*   h1bf = (u16*)(W + 16777216);     // 1024x2048 bf16
    float* partA = (float*)(W + 131072000); // 1024x8192 f32 (nsa split-K partial 0)
    float* partB = (float*)(W + 25165824);  // 1024x8192 f32 (partial 1, dead W_ih)
    u16*   lnbf = Xbf;
    u16*   q2   = q0;
    u16*   att2 = att1;
    float* hW2  = (float*)(W + 131072000);  // 8 partials 64x8192 f32 = 16.8 MB
    float* h2   = (float*)(W + 147849216);  // inside dead att2 region
    float* c2   = (float*)(W + 148373504);
    u16*   h2bf = (u16*)(W + 148897792);

    // 0) convert fc + nsa weights + sa_Whh to bf16
    {
        CvtArgs a{};
        a.src[0] = fc;      a.dst[0] = Xbf;   a.n4[0] = 655360;
        a.src[1] = nsa_Wq;  a.dst[1] = W_q;   a.n4[1] = 1048576;
        a.src[2] = nsa_Wk;  a.dst[2] = W_k;   a.n4[2] = 1048576;
        a.src[3] = nsa_Wv;  a.dst[3] = W_v;   a.n4[3] = 1048576;
        a.src[4] = nsa_Wih; a.dst[4] = W_ih;  a.n4[4] = 4194304;
        a.src[5] = nsa_Whh; a.dst[5] = W_hh1; a.n4[5] = 4194304;
        a.src[6] = sa_Whh;  a.dst[6] = W_hh2; a.n4[6] = 4194304;
        a.nseg = 7;
        cvt_multi<<<2048, 256, 0, stream>>>(a);
    }

    // 1) nsa QKV on the 1280 unique rows (z=3, 480 blocks)
    launch_qkv(stream, Xbf, W_q, W_k, W_v, nsa_bq, nsa_bk, nsa_bv, q0, 1280, 2048, 2048);

    // 2) windowed attention
    attn_win5<<<1024, 256, 0, stream>>>(q0, q0 + 2621440, q0 + 5242880, att1);

    // 3) xg for ALL 5 steps: one M=5120 8-phase GEMM (640 blocks), bf16 out
    gemm256<1, true><<<dim3(32, 20, 1), 512, 0, stream>>>(att1, 2048, W_ih,
                                                          xg, nullptr, 5120, 8192, 2048);

    // 4) nsa LSTM over 5 steps (rows = 1024 windows); recurrent = split-K=2 8-phase
    lstm_gate<0><<<2048, 256, 0, stream>>>(xg, 40960, nullptr, nullptr, nsa_bih,
                                           nsa_bhh, c1, h1, h1bf, nullptr, 1024);
    for (int t = 1; t < 5; ++t) {
        gemm256<2, false><<<dim3(32, 4, 2), 512, 0, stream>>>(h1bf, 2048, W_hh1,
                                                              partA, partB, 1024, 8192, 2048);
        lstm_gate<2><<<2048, 256, 0, stream>>>(xg + (size_t)t * 8192, 40960, partA,
                                               partB, nsa_bih, nsa_bhh, c1, h1, h1bf,
                                               nullptr, 1024);
    }

    // 5) LayerNorm -> output 1 (fp32) + bf16 copy for stage 2
    layernorm_k<<<1024, 256, 0, stream>>>(h1, ln_g, ln_b, out_ln, lnbf);

    // 5b) convert sa single-use weights into the (now dead) nsa slots
    {
        CvtArgs a{};
        a.src[0] = sa_Wq;  a.dst[0] = W_q;  a.n4[0] = 1048576;
        a.src[1] = sa_Wk;  a.dst[1] = W_k;  a.n4[1] = 1048576;
        a.src[2] = sa_Wv;  a.dst[2] = W_v;  a.n4[2] = 1048576;
        a.src[3] = sa_Wih; a.dst[3] = W_ih; a.n4[3] = 4194304;
        a.nseg = 4;
        cvt_multi<<<2048, 256, 0, stream>>>(a);
    }

    // 6) sa QKV (z=3, 384 blocks)
    launch_qkv(stream, lnbf, W_q, W_k, W_v, sa_bq, sa_bk, sa_bv, q2, 1024, 2048, 2048);

    // 7) seq-16 attention
    attn_seq16<<<1024, 256, 0, stream>>>(q2, q2 + 2097152, q2 + 4194304, att2);

    // 8) xg2 = att2 @ saWih^T (8-phase, 128 blocks, bf16 out)
    gemm256<1, true><<<dim3(32, 4, 1), 512, 0, stream>>>(att2, 2048, W_ih,
                                                         xg, nullptr, 1024, 8192, 2048);

    // 9) sa LSTM over 16 steps (rows = 64); recurrent GEMM = skinny split-K=8
    lstm_gate<0><<<128, 256, 0, stream>>>(xg, 131072, nullptr, nullptr, sa_bih,
                                          sa_bhh, c2, h2, h2bf, nullptr, 64);
    for (int t = 1; t < 16; ++t) {
        gemm_skinny64<<<dim3(64, 8), 256, 0, stream>>>(h2bf, W_hh2, hW2, 8192, 2048);
        lstm_gate<8><<<128, 256, 0, stream>>>(xg + (size_t)t * 8192, 131072, hW2,
                                              nullptr, sa_bih, sa_bhh, c2, h2, h2bf,
                                              (t == 15) ? out_sa : nullptr, 64);
    }
}